// Round 2
// baseline (2129.485 us; speedup 1.0000x reference)
//
#include <hip/hip_runtime.h>
#include <math.h>

#define H 128
#define LAYERS 3
#define FFDIM 256
#define JK 384
#define ATT_SCALE 0.17677669529663687f

typedef unsigned short u16;

static inline int cdiv(int a, int b) { return (a + b - 1) / b; }

static __device__ __forceinline__ float bf2f(u16 u) {
    union { unsigned int i; float f; } v; v.i = ((unsigned int)u) << 16; return v.f;
}
static __device__ __forceinline__ u16 f2bf(float f) {
    union { float f; unsigned int i; } v; v.f = f;
    unsigned int r = v.i + 0x7FFFu + ((v.i >> 16) & 1u);
    return (u16)(r >> 16);
}

// ---------------- CSR build over dst ----------------
__global__ void hist_kernel(const int* __restrict__ ei, int* __restrict__ counts, int E) {
    int e = blockIdx.x * blockDim.x + threadIdx.x;
    if (e >= E) return;
    atomicAdd(&counts[ei[E + e]], 1);
}

__global__ __launch_bounds__(1024) void scan_kernel(const int* __restrict__ counts,
                                                    int* __restrict__ offsets, int N) {
    __shared__ int part[1024];
    int t = threadIdx.x;
    int CH = (N + 1023) >> 10;
    int base = t * CH;
    int s = 0;
    for (int i = 0; i < CH; ++i) {
        int idx = base + i;
        if (idx < N) s += counts[idx];
    }
    part[t] = s;
    __syncthreads();
    for (int off = 1; off < 1024; off <<= 1) {
        int tmp = (t >= off) ? part[t - off] : 0;
        __syncthreads();
        part[t] += tmp;
        __syncthreads();
    }
    int run = part[t] - s;  // exclusive prefix
    for (int i = 0; i < CH; ++i) {
        int idx = base + i;
        if (idx < N) { offsets[idx] = run; run += counts[idx]; }
    }
    if (t == 1023) offsets[N] = part[1023];
}

__global__ void scatter_kernel(const int* __restrict__ ei, const int* __restrict__ offsets,
                               int* __restrict__ cursor, int* __restrict__ perm, int E) {
    int e = blockIdx.x * blockDim.x + threadIdx.x;
    if (e >= E) return;
    int d = ei[E + e];
    int pos = atomicAdd(&cursor[d], 1);
    perm[offsets[d] + pos] = e;
}

__global__ void graph_bounds_kernel(const int* __restrict__ batch, int* __restrict__ gstart,
                                    int N, int G) {
    int g = blockIdx.x * blockDim.x + threadIdx.x;
    if (g > G) return;
    int lo = 0, hi = N;
    while (lo < hi) { int mid = (lo + hi) >> 1; if (batch[mid] < g) lo = mid + 1; else hi = mid; }
    gstart[g] = lo;
}

// ---------------- input projection h0 = x @ Win + b -> bf16, strided into xc cols 0..127
__global__ __launch_bounds__(256) void input_proj_kernel(const float* __restrict__ x,
                                                         const float* __restrict__ Win,
                                                         const float* __restrict__ b_in,
                                                         u16* __restrict__ h, int ldh, int N) {
    int idx = blockIdx.x * 256 + threadIdx.x;     // N*64 threads, 2 cols each
    int n = idx >> 6, c = (idx & 63) * 2;
    if (n >= N) return;
    float4 xv = *(const float4*)&x[(size_t)n * 4];
    float o0 = b_in[c]     + xv.x * Win[c]     + xv.y * Win[H + c]     + xv.z * Win[2 * H + c]     + xv.w * Win[3 * H + c];
    float o1 = b_in[c + 1] + xv.x * Win[c + 1] + xv.y * Win[H + c + 1] + xv.z * Win[2 * H + c + 1] + xv.w * Win[3 * H + c + 1];
    ushort2 s; s.x = f2bf(o0); s.y = f2bf(o1);
    *(ushort2*)&h[(size_t)n * ldh + c] = s;
}

// ---------------- generic GEMM: out[n,c] = A[n,:K] @ W[:K, wcol+c] (+bias)(+resid)(relu)
// A: f32 or bf16 (A_BF16); out: f32 or bf16 (O_BF16); W, bias, resid always f32.
#define BM 128
#define BK 64

template <bool A_BF16, bool O_BF16>
__global__ __launch_bounds__(256) void gemm_kernel(
    const void* __restrict__ Av, int lda,
    const float* __restrict__ W, int ldw, int wcol,
    const float* __restrict__ bias,
    const float* __restrict__ resid, int ldr,
    void* __restrict__ outv, int ldo,
    int nrows, int K, int relu)
{
    __shared__ float Wl[BK][132];
    __shared__ float Hl[BK][132];   // transposed: Hl[k][row]
    int t = threadIdx.x;
    int row0 = blockIdx.x * BM;
    int c0 = (t & 15) * 8;
    int r0 = (t >> 4) * 8;
    float acc[8][8];
#pragma unroll
    for (int i = 0; i < 8; ++i)
#pragma unroll
        for (int j = 0; j < 8; ++j) acc[i][j] = 0.f;

    for (int kt = 0; kt < K; kt += BK) {
#pragma unroll
        for (int i = 0; i < 8; ++i) {          // W tile: 64x128
            int f = t + i * 256;
            int wr = f >> 5;
            int wc = (f & 31) * 4;
            float4 v = *(const float4*)&W[(size_t)(kt + wr) * ldw + wcol + wc];
            *(float4*)&Wl[wr][wc] = v;
        }
#pragma unroll
        for (int i = 0; i < 8; ++i) {          // A tile: 128 rows x 64 k, transposed
            int f = t + i * 256;
            int r = f >> 4;
            int k4 = (f & 15) * 4;
            int n = row0 + r; if (n >= nrows) n = nrows - 1;
            float v0, v1, v2, v3;
            if (A_BF16) {
                const u16* A = (const u16*)Av;
                ushort4 u = *(const ushort4*)&A[(size_t)n * lda + kt + k4];
                v0 = bf2f(u.x); v1 = bf2f(u.y); v2 = bf2f(u.z); v3 = bf2f(u.w);
            } else {
                const float* A = (const float*)Av;
                float4 v = *(const float4*)&A[(size_t)n * lda + kt + k4];
                v0 = v.x; v1 = v.y; v2 = v.z; v3 = v.w;
            }
            Hl[k4 + 0][r] = v0; Hl[k4 + 1][r] = v1; Hl[k4 + 2][r] = v2; Hl[k4 + 3][r] = v3;
        }
        __syncthreads();
#pragma unroll 4
        for (int k = 0; k < BK; ++k) {
            float4 ha = *(const float4*)&Hl[k][r0];
            float4 hb = *(const float4*)&Hl[k][r0 + 4];
            float4 wa = *(const float4*)&Wl[k][c0];
            float4 wb = *(const float4*)&Wl[k][c0 + 4];
            float hr[8] = {ha.x, ha.y, ha.z, ha.w, hb.x, hb.y, hb.z, hb.w};
            float wv[8] = {wa.x, wa.y, wa.z, wa.w, wb.x, wb.y, wb.z, wb.w};
#pragma unroll
            for (int i = 0; i < 8; ++i)
#pragma unroll
                for (int j = 0; j < 8; ++j)
                    acc[i][j] = fmaf(hr[i], wv[j], acc[i][j]);
        }
        __syncthreads();
    }

    float4 ba = *(const float4*)&bias[c0];
    float4 bb = *(const float4*)&bias[c0 + 4];
    float bv[8] = {ba.x, ba.y, ba.z, ba.w, bb.x, bb.y, bb.z, bb.w};
#pragma unroll
    for (int i = 0; i < 8; ++i) {
        int n = row0 + r0 + i;
        if (n >= nrows) break;
        float o[8];
#pragma unroll
        for (int j = 0; j < 8; ++j) o[j] = acc[i][j] + bv[j];
        if (resid) {
            float4 ra = *(const float4*)&resid[(size_t)n * ldr + c0];
            float4 rb = *(const float4*)&resid[(size_t)n * ldr + c0 + 4];
            o[0] += ra.x; o[1] += ra.y; o[2] += ra.z; o[3] += ra.w;
            o[4] += rb.x; o[5] += rb.y; o[6] += rb.z; o[7] += rb.w;
        }
        if (relu) {
#pragma unroll
            for (int j = 0; j < 8; ++j) o[j] = fmaxf(o[j], 0.f);
        }
        if (O_BF16) {
            u16* out = (u16*)outv;
            ushort4 s0, s1;
            s0.x = f2bf(o[0]); s0.y = f2bf(o[1]); s0.z = f2bf(o[2]); s0.w = f2bf(o[3]);
            s1.x = f2bf(o[4]); s1.y = f2bf(o[5]); s1.z = f2bf(o[6]); s1.w = f2bf(o[7]);
            *(ushort4*)&out[(size_t)n * ldo + c0]     = s0;
            *(ushort4*)&out[(size_t)n * ldo + c0 + 4] = s1;
        } else {
            float* out = (float*)outv;
            *(float4*)&out[(size_t)n * ldo + c0]     = make_float4(o[0], o[1], o[2], o[3]);
            *(float4*)&out[(size_t)n * ldo + c0 + 4] = make_float4(o[4], o[5], o[6], o[7]);
        }
    }
}

// ---------------- per-node attention + LN1 (one wave per dst node) ----------------
// qkv: [N,384] bf16 (q|k|v). hmid holds skip (f32) on entry; overwritten with LN1 output.
__global__ __launch_bounds__(256) void attn_kernel(
    const u16* __restrict__ qkv,
    const u16* __restrict__ h_in, int ld_h,
    const int* __restrict__ offsets, const int* __restrict__ perm,
    const int* __restrict__ esrc, const float* __restrict__ eattr,
    const float* __restrict__ We_l,
    const float* __restrict__ g1, const float* __restrict__ b1,
    float* __restrict__ hmid, int N)
{
    int wid = threadIdx.x >> 6;
    int lane = threadIdx.x & 63;
    int n = blockIdx.x * 4 + wid;
    if (n >= N) return;
    int d0 = lane * 2;

    float we0[4], we1[4];
#pragma unroll
    for (int i = 0; i < 4; ++i) { we0[i] = We_l[i * H + d0]; we1[i] = We_l[i * H + d0 + 1]; }

    ushort2 qraw = *(const ushort2*)&qkv[(size_t)n * JK + d0];
    float q0 = bf2f(qraw.x), q1 = bf2f(qraw.y);
    float m = -INFINITY, ssum = 0.f, a0 = 0.f, a1 = 0.f;
    int e0 = offsets[n], e1 = offsets[n + 1];
    for (int j = e0; j < e1; ++j) {
        int e = perm[j];
        int s = esrc[e];
        const u16* srow = qkv + (size_t)s * JK;
        float4 ea = *(const float4*)&eattr[(size_t)e * 4];
        float eb0 = ea.x * we0[0] + ea.y * we0[1] + ea.z * we0[2] + ea.w * we0[3];
        float eb1 = ea.x * we1[0] + ea.y * we1[1] + ea.z * we1[2] + ea.w * we1[3];
        ushort2 kraw = *(const ushort2*)&srow[H + d0];
        ushort2 vraw = *(const ushort2*)&srow[2 * H + d0];
        float k0 = bf2f(kraw.x) + eb0, k1 = bf2f(kraw.y) + eb1;
        float v0 = bf2f(vraw.x) + eb0, v1 = bf2f(vraw.y) + eb1;
        float part = q0 * k0 + q1 * k1;
        part += __shfl_xor(part, 1, 16);
        part += __shfl_xor(part, 2, 16);
        part += __shfl_xor(part, 4, 16);
        part += __shfl_xor(part, 8, 16);
        float logit = part * ATT_SCALE;
        float mn = fmaxf(m, logit);
        float corr = __expf(m - mn);       // m = -inf first edge -> corr = 0
        float p = __expf(logit - mn);
        ssum = ssum * corr + p;
        a0 = a0 * corr + p * v0;
        a1 = a1 * corr + p * v1;
        m = mn;
    }
    float inv = 1.f / (ssum + 1e-16f);
    a0 *= inv; a1 *= inv;

    ushort2 hraw = *(const ushort2*)&h_in[(size_t)n * ld_h + d0];
    float2 sk = *(const float2*)&hmid[(size_t)n * H + d0];
    float t0 = bf2f(hraw.x) + a0 + sk.x;
    float t1 = bf2f(hraw.y) + a1 + sk.y;
    float sum = t0 + t1, sq = t0 * t0 + t1 * t1;
#pragma unroll
    for (int off = 32; off; off >>= 1) { sum += __shfl_xor(sum, off); sq += __shfl_xor(sq, off); }
    float mean = sum * (1.f / 128.f);
    float var = sq * (1.f / 128.f) - mean * mean;
    float rstd = rsqrtf(var + 1e-5f);
    float2 o;
    o.x = (t0 - mean) * rstd * g1[d0] + b1[d0];
    o.y = (t1 - mean) * rstd * g1[d0 + 1] + b1[d0 + 1];
    *(float2*)&hmid[(size_t)n * H + d0] = o;
}

// ---------------- LayerNorm f32 in -> bf16 out (wave per row) ----------------
__global__ __launch_bounds__(256) void ln_kernel(const float* __restrict__ in,
                                                 const float* __restrict__ g,
                                                 const float* __restrict__ b,
                                                 u16* __restrict__ out, int ldo, int N) {
    int wid = threadIdx.x >> 6;
    int lane = threadIdx.x & 63;
    int n = blockIdx.x * 4 + wid;
    if (n >= N) return;
    int d0 = lane * 2;
    float2 t = *(const float2*)&in[(size_t)n * H + d0];
    float sum = t.x + t.y, sq = t.x * t.x + t.y * t.y;
#pragma unroll
    for (int off = 32; off; off >>= 1) { sum += __shfl_xor(sum, off); sq += __shfl_xor(sq, off); }
    float mean = sum * (1.f / 128.f);
    float var = sq * (1.f / 128.f) - mean * mean;
    float rstd = rsqrtf(var + 1e-5f);
    ushort2 s;
    s.x = f2bf((t.x - mean) * rstd * g[d0] + b[d0]);
    s.y = f2bf((t.y - mean) * rstd * g[d0 + 1] + b[d0 + 1]);
    *(ushort2*)&out[(size_t)n * ldo + d0] = s;
}

// ---------------- gate scalar: gate[n] = ghid[n,:] . Wg2 + bg2 ----------------
__global__ __launch_bounds__(256) void gate2_kernel(const float* __restrict__ ghid,
                                                    const float* __restrict__ Wg2,
                                                    const float* __restrict__ bg2,
                                                    float* __restrict__ gate, int N) {
    int wid = threadIdx.x >> 6;
    int lane = threadIdx.x & 63;
    int n = blockIdx.x * 4 + wid;
    if (n >= N) return;
    int d0 = lane * 2;
    float2 hv = *(const float2*)&ghid[(size_t)n * H + d0];
    float v = hv.x * Wg2[d0] + hv.y * Wg2[d0 + 1];
#pragma unroll
    for (int off = 32; off; off >>= 1) v += __shfl_xor(v, off);
    if (lane == 0) gate[n] = v + bg2[0];
}

// ---------------- per-graph softmax pooling ----------------
__global__ __launch_bounds__(256) void pool_kernel(const float* __restrict__ gate,
                                                   const u16* __restrict__ xc,
                                                   const int* __restrict__ gstart,
                                                   const float* __restrict__ u,
                                                   float* __restrict__ pooled, int G) {
    int g = blockIdx.x;
    int t = threadIdx.x;
    int s0 = gstart[g], s1 = gstart[g + 1];
    __shared__ float red[256];
    float mx = -INFINITY;
    for (int i = s0 + t; i < s1; i += 256) mx = fmaxf(mx, gate[i]);
    red[t] = mx; __syncthreads();
    for (int off = 128; off; off >>= 1) { if (t < off) red[t] = fmaxf(red[t], red[t + off]); __syncthreads(); }
    float gm = red[0]; __syncthreads();
    float sm = 0.f;
    for (int i = s0 + t; i < s1; i += 256) sm += __expf(gate[i] - gm);
    red[t] = sm; __syncthreads();
    for (int off = 128; off; off >>= 1) { if (t < off) red[t] += red[t + off]; __syncthreads(); }
    float inv = 1.f / (red[0] + 1e-16f);
    for (int d = t; d < JK; d += 256) {
        float acc = 0.f;
        for (int i = s0; i < s1; ++i)
            acc += __expf(gate[i] - gm) * bf2f(xc[(size_t)i * JK + d]);
        pooled[(size_t)g * (JK + 1) + d] = acc * inv;
    }
    if (t == 0) pooled[(size_t)g * (JK + 1) + JK] = u[g];
}

// ---------------- final MLP head ----------------
__global__ __launch_bounds__(128) void head_kernel(const float* __restrict__ pooled,
                                                   const float* __restrict__ Wh1,
                                                   const float* __restrict__ bh1,
                                                   const float* __restrict__ Wh2,
                                                   const float* __restrict__ bh2,
                                                   float* __restrict__ out, int G) {
    int g = blockIdx.x;
    int j = threadIdx.x;
    __shared__ float hid[128];
    float acc = bh1[j];
    const float* pr = pooled + (size_t)g * (JK + 1);
    for (int k = 0; k < JK + 1; ++k) acc = fmaf(pr[k], Wh1[(size_t)k * H + j], acc);
    hid[j] = fmaxf(acc, 0.f);
    __syncthreads();
    if (j < 3) {
        float o = bh2[j];
        for (int k = 0; k < H; ++k) o += hid[k] * Wh2[k * 3 + j];
        out[(size_t)g * 3 + j] = o;
    }
}

extern "C" void kernel_launch(void* const* d_in, const int* in_sizes, int n_in,
                              void* d_out, int out_size, void* d_ws, size_t ws_size,
                              hipStream_t stream) {
    const float* x     = (const float*)d_in[0];
    const int*   ei    = (const int*)d_in[1];
    const float* eattr = (const float*)d_in[2];
    const int*   batch = (const int*)d_in[3];
    const float* u     = (const float*)d_in[4];
    const float* Win   = (const float*)d_in[5];
    const float* b_in  = (const float*)d_in[6];
    const float* Wq    = (const float*)d_in[7];
    const float* bq    = (const float*)d_in[8];
    const float* Wk    = (const float*)d_in[9];
    const float* bk    = (const float*)d_in[10];
    const float* Wv    = (const float*)d_in[11];
    const float* bv    = (const float*)d_in[12];
    const float* We    = (const float*)d_in[13];
    const float* Wskip = (const float*)d_in[14];
    const float* bskip = (const float*)d_in[15];
    const float* ln1_g = (const float*)d_in[16];
    const float* ln1_b = (const float*)d_in[17];
    const float* Wf1   = (const float*)d_in[18];
    const float* bf1   = (const float*)d_in[19];
    const float* Wf2   = (const float*)d_in[20];
    const float* bf2   = (const float*)d_in[21];
    const float* ln2_g = (const float*)d_in[22];
    const float* ln2_b = (const float*)d_in[23];
    const float* Wg1   = (const float*)d_in[24];
    const float* bg1   = (const float*)d_in[25];
    const float* Wg2   = (const float*)d_in[26];
    const float* bg2   = (const float*)d_in[27];
    const float* Wh1   = (const float*)d_in[28];
    const float* bh1   = (const float*)d_in[29];
    const float* Wh2   = (const float*)d_in[30];
    const float* bh2   = (const float*)d_in[31];

    const int N = in_sizes[3];
    const int E = in_sizes[1] / 2;
    const int G = in_sizes[4];

    // workspace carve-up (256B aligned) — total ~210 MB
    char* p = (char*)d_ws;
    auto alloc = [&](size_t bytes) { char* r = p; p += (bytes + 255) & ~(size_t)255; return r; };
    int*   counts  = (int*)alloc((size_t)N * 4);
    int*   cursor  = (int*)alloc((size_t)N * 4);
    int*   offsets = (int*)alloc((size_t)(N + 1) * 4);
    int*   perm    = (int*)alloc((size_t)E * 4);
    int*   gstart  = (int*)alloc((size_t)(G + 1) * 4);
    float* gate    = (float*)alloc((size_t)N * 4);
    float* pooled  = (float*)alloc((size_t)G * (JK + 1) * 4);
    float* hmid    = (float*)alloc((size_t)N * H * 4);            // f32 [N,128]
    u16*   xc      = (u16*)alloc((size_t)N * JK * 2);             // bf16 [N,384]; h0 lives in cols 0..127 until LN2 of layer 0
    u16*   qkv     = (u16*)alloc((size_t)N * JK * 2);             // bf16 [N,384] q|k|v; aliased below
    u16*   ff1     = qkv;                                         // bf16 [N,256] (qkv dead after attn)
    float* ghid    = (float*)qkv;                                 // f32 [N,128] (region is 76.8MB >= 51.2MB)

    hipMemsetAsync(counts, 0, (size_t)N * 4, stream);
    hipMemsetAsync(cursor, 0, (size_t)N * 4, stream);

    int eb = cdiv(E, 256);
    hist_kernel<<<eb, 256, 0, stream>>>(ei, counts, E);
    scan_kernel<<<1, 1024, 0, stream>>>(counts, offsets, N);
    scatter_kernel<<<eb, 256, 0, stream>>>(ei, offsets, cursor, perm, E);
    graph_bounds_kernel<<<cdiv(G + 1, 256), 256, 0, stream>>>(batch, gstart, N, G);

    input_proj_kernel<<<cdiv(N * 64, 256), 256, 0, stream>>>(x, Win, b_in, xc, JK, N);

    int gb = cdiv(N, BM);
    int nb4 = cdiv(N, 4);
    for (int l = 0; l < LAYERS; ++l) {
        const u16* hin = xc + (size_t)((l == 0) ? 0 : (l - 1) * H);
        // q,k,v -> bf16 qkv; skip -> f32 hmid
        gemm_kernel<true, true><<<gb, 256, 0, stream>>>(hin, JK, Wq + (size_t)l * H * H, H, 0, bq + l * H,
                                                        nullptr, 0, qkv + 0, JK, N, H, 0);
        gemm_kernel<true, true><<<gb, 256, 0, stream>>>(hin, JK, Wk + (size_t)l * H * H, H, 0, bk + l * H,
                                                        nullptr, 0, qkv + H, JK, N, H, 0);
        gemm_kernel<true, true><<<gb, 256, 0, stream>>>(hin, JK, Wv + (size_t)l * H * H, H, 0, bv + l * H,
                                                        nullptr, 0, qkv + 2 * H, JK, N, H, 0);
        gemm_kernel<true, false><<<gb, 256, 0, stream>>>(hin, JK, Wskip + (size_t)l * H * H, H, 0, bskip + l * H,
                                                         nullptr, 0, hmid, H, N, H, 0);
        attn_kernel<<<nb4, 256, 0, stream>>>(qkv, hin, JK, offsets, perm, ei, eattr,
                                             We + (size_t)l * 4 * H, ln1_g + l * H, ln1_b + l * H,
                                             hmid, N);
        // FF: hmid(f32) -> ff1(bf16, 256 cols via two 128-col GEMMs) -> hmid(f32, +resid)
        gemm_kernel<false, true><<<gb, 256, 0, stream>>>(hmid, H, Wf1 + (size_t)l * H * FFDIM, FFDIM, 0,
                                                         bf1 + (size_t)l * FFDIM, nullptr, 0, ff1 + 0, FFDIM, N, H, 1);
        gemm_kernel<false, true><<<gb, 256, 0, stream>>>(hmid, H, Wf1 + (size_t)l * H * FFDIM, FFDIM, H,
                                                         bf1 + (size_t)l * FFDIM + H, nullptr, 0, ff1 + H, FFDIM, N, H, 1);
        gemm_kernel<true, false><<<gb, 256, 0, stream>>>(ff1, FFDIM, Wf2 + (size_t)l * FFDIM * H, H, 0,
                                                         bf2 + (size_t)l * H, hmid, H, hmid, H, N, FFDIM, 0);
        ln_kernel<<<nb4, 256, 0, stream>>>(hmid, ln2_g + l * H, ln2_b + l * H,
                                           xc + (size_t)l * H, JK, N);
    }

    gemm_kernel<true, false><<<gb, 256, 0, stream>>>(xc, JK, Wg1, H, 0, bg1, nullptr, 0, ghid, H, N, JK, 1);
    gate2_kernel<<<nb4, 256, 0, stream>>>(ghid, Wg2, bg2, gate, N);
    pool_kernel<<<G, 256, 0, stream>>>(gate, xc, gstart, u, pooled, G);
    head_kernel<<<G, 128, 0, stream>>>(pooled, Wh1, bh1, Wh2, bh2, (float*)d_out, G);
}

// Round 3
// 1085.380 us; speedup vs baseline: 1.9620x; 1.9620x over previous
//
#include <hip/hip_runtime.h>
#include <math.h>

#define H 128
#define LAYERS 3
#define FFDIM 256
#define JK 384
#define ATT_SCALE 0.17677669529663687f

typedef unsigned short u16;
typedef __attribute__((ext_vector_type(4))) float f32x4;
typedef __attribute__((ext_vector_type(8))) short short8;

static inline int cdiv(int a, int b) { return (a + b - 1) / b; }

static __device__ __forceinline__ float bf2f(u16 u) {
    union { unsigned int i; float f; } v; v.i = ((unsigned int)u) << 16; return v.f;
}
static __device__ __forceinline__ u16 f2bf(float f) {
    union { float f; unsigned int i; } v; v.f = f;
    unsigned int r = v.i + 0x7FFFu + ((v.i >> 16) & 1u);
    return (u16)(r >> 16);
}

// ---------------- CSR build over dst ----------------
__global__ void hist_kernel(const int* __restrict__ ei, int* __restrict__ counts, int E) {
    int e = blockIdx.x * blockDim.x + threadIdx.x;
    if (e >= E) return;
    atomicAdd(&counts[ei[E + e]], 1);
}

// 3-phase scan: block-local scan -> block-sum scan -> add back
__global__ __launch_bounds__(256) void scan1_kernel(const int* __restrict__ counts,
                                                    int* __restrict__ offsets,
                                                    int* __restrict__ bsum, int N) {
    __shared__ int sh[256];
    int t = threadIdx.x;
    int base = blockIdx.x * 1024 + t * 4;
    int v0 = 0, v1 = 0, v2 = 0, v3 = 0;
    if (base + 3 < N) {
        int4 q = *(const int4*)&counts[base];
        v0 = q.x; v1 = q.y; v2 = q.z; v3 = q.w;
    } else {
        if (base < N) v0 = counts[base];
        if (base + 1 < N) v1 = counts[base + 1];
        if (base + 2 < N) v2 = counts[base + 2];
        if (base + 3 < N) v3 = counts[base + 3];
    }
    int ts = v0 + v1 + v2 + v3;
    sh[t] = ts; __syncthreads();
    for (int off = 1; off < 256; off <<= 1) {
        int x = (t >= off) ? sh[t - off] : 0;
        __syncthreads(); sh[t] += x; __syncthreads();
    }
    int excl = sh[t] - ts;
    if (base < N)     offsets[base]     = excl;
    if (base + 1 < N) offsets[base + 1] = excl + v0;
    if (base + 2 < N) offsets[base + 2] = excl + v0 + v1;
    if (base + 3 < N) offsets[base + 3] = excl + v0 + v1 + v2;
    if (t == 255) bsum[blockIdx.x] = sh[255];
}

__global__ __launch_bounds__(128) void scan2_kernel(const int* __restrict__ bsum,
                                                    int* __restrict__ boffs,
                                                    int* __restrict__ offsets, int nb, int N) {
    __shared__ int sh[128];
    int t = threadIdx.x;
    int s = (t < nb) ? bsum[t] : 0;
    sh[t] = s; __syncthreads();
    for (int off = 1; off < 128; off <<= 1) {
        int x = (t >= off) ? sh[t - off] : 0;
        __syncthreads(); sh[t] += x; __syncthreads();
    }
    if (t < nb) boffs[t] = sh[t] - s;
    if (t == 0) offsets[N] = sh[nb - 1];
}

__global__ __launch_bounds__(256) void scan3_kernel(int* __restrict__ offsets,
                                                    const int* __restrict__ boffs, int N) {
    int add = boffs[blockIdx.x];
    int base = blockIdx.x * 1024 + threadIdx.x * 4;
#pragma unroll
    for (int i = 0; i < 4; ++i)
        if (base + i < N) offsets[base + i] += add;
}

__global__ void scatter_kernel(const int* __restrict__ ei, const int* __restrict__ offsets,
                               int* __restrict__ cursor, int* __restrict__ perm, int E) {
    int e = blockIdx.x * blockDim.x + threadIdx.x;
    if (e >= E) return;
    int d = ei[E + e];
    int pos = atomicAdd(&cursor[d], 1);
    perm[offsets[d] + pos] = e;
}

__global__ void graph_bounds_kernel(const int* __restrict__ batch, int* __restrict__ gstart,
                                    int N, int G) {
    int g = blockIdx.x * blockDim.x + threadIdx.x;
    if (g > G) return;
    int lo = 0, hi = N;
    while (lo < hi) { int mid = (lo + hi) >> 1; if (batch[mid] < g) lo = mid + 1; else hi = mid; }
    gstart[g] = lo;
}

// ---------------- weight transpose+convert: WT[c*K+k] = bf16(W[k*N+c]) ----------------
struct TD { const float* src; int dstoff, K, N; };
struct TA { TD d[19]; };

__global__ __launch_bounds__(256) void wconv_kernel(TA a, u16* __restrict__ WT) {
    TD d = a.d[blockIdx.y];
    int i = blockIdx.x * 256 + threadIdx.x;
    int tot = d.K * d.N;
    if (i >= tot) return;
    int c = i / d.K, k = i - c * d.K;
    WT[d.dstoff + i] = f2bf(d.src[(size_t)k * d.N + c]);
}

// ---------------- input projection h0 = x @ Win + b -> bf16, strided into xc cols 0..127
__global__ __launch_bounds__(256) void input_proj_kernel(const float* __restrict__ x,
                                                         const float* __restrict__ Win,
                                                         const float* __restrict__ b_in,
                                                         u16* __restrict__ h, int ldh, int N) {
    int idx = blockIdx.x * 256 + threadIdx.x;     // N*64 threads, 2 cols each
    int n = idx >> 6, c = (idx & 63) * 2;
    if (n >= N) return;
    float4 xv = *(const float4*)&x[(size_t)n * 4];
    float o0 = b_in[c]     + xv.x * Win[c]     + xv.y * Win[H + c]     + xv.z * Win[2 * H + c]     + xv.w * Win[3 * H + c];
    float o1 = b_in[c + 1] + xv.x * Win[c + 1] + xv.y * Win[H + c + 1] + xv.z * Win[2 * H + c + 1] + xv.w * Win[3 * H + c + 1];
    ushort2 s; s.x = f2bf(o0); s.y = f2bf(o1);
    *(ushort2*)&h[(size_t)n * ldh + c] = s;
}

// ---------------- MFMA bf16 GEMM ----------------
// C[M,128] = A[M,K](bf16) @ WT[128,K]^T(bf16), XOR-swizzled LDS tiles, 4 waves x (64x64).
// MODE 0: qkv+skip  (grid.y=4; by<3 -> bf16 out at obf+by*128 ld 384; by==3 -> f32 of32 ld 128)
// MODE 1: ff1       (grid.y=2; bias b0+by*128; relu; bf16 out obf+by*128 ld 384)
// MODE 2: ff2       (resid f32 += ; f32 out ld 128)
// MODE 3: gate1     (relu; f32 out ld 128)
__device__ __forceinline__ void stage_tile(const u16* __restrict__ g, int ld, int row0,
                                           int nrows, int kt, u16* __restrict__ sm, int t) {
#pragma unroll
    for (int i = 0; i < 4; ++i) {
        int f = i * 256 + t;              // chunk id 0..1023
        int row = f >> 3, ck = f & 7;
        int n = row0 + row; if (n >= nrows) n = nrows - 1;
        uint4 v = *(const uint4*)(g + (size_t)n * ld + kt + ck * 8);
        int sw = ck ^ (row & 7);
        *(uint4*)(sm + row * 64 + sw * 8) = v;
    }
}

template <int MODE>
__global__ __launch_bounds__(256) void gemm_mfma(
    const u16* __restrict__ A, int lda,
    const u16* __restrict__ WT, int K,
    const float* __restrict__ b0, const float* __restrict__ b1,
    const float* __restrict__ b2, const float* __restrict__ b3,
    const float* __restrict__ resid,
    u16* __restrict__ obf, float* __restrict__ of32,
    int nrows)
{
    alignas(16) __shared__ u16 Asm[128 * 64];
    alignas(16) __shared__ u16 Bsm[128 * 64];
    int t = threadIdx.x;
    int lane = t & 63, wid = t >> 6;
    int wr = wid >> 1, wc = wid & 1;
    int row0 = blockIdx.x * 128;
    int by = blockIdx.y;
    const u16* WTb = WT + (size_t)by * 128 * K;

    f32x4 acc[4][4] = {};

    for (int kt = 0; kt < K; kt += 64) {
        stage_tile(A, lda, row0, nrows, kt, Asm, t);
        stage_tile(WTb, K, 0, 128, kt, Bsm, t);
        __syncthreads();
        int g = lane >> 4;
        int l15 = lane & 15;
#pragma unroll
        for (int kk = 0; kk < 2; ++kk) {
            int cb = kk * 4 + g;
            short8 af[4], bf[4];
#pragma unroll
            for (int mi = 0; mi < 4; ++mi) {
                int r = wr * 64 + mi * 16 + l15;
                af[mi] = *(const short8*)(Asm + r * 64 + ((cb ^ (r & 7)) * 8));
            }
#pragma unroll
            for (int nj = 0; nj < 4; ++nj) {
                int c = wc * 64 + nj * 16 + l15;
                bf[nj] = *(const short8*)(Bsm + c * 64 + ((cb ^ (c & 7)) * 8));
            }
#pragma unroll
            for (int mi = 0; mi < 4; ++mi)
#pragma unroll
                for (int nj = 0; nj < 4; ++nj)
                    acc[mi][nj] = __builtin_amdgcn_mfma_f32_16x16x32_bf16(af[mi], bf[nj], acc[mi][nj], 0, 0, 0);
        }
        __syncthreads();
    }

    const float* bias;
    u16* ob = nullptr; float* of = nullptr;
    if (MODE == 0) {
        bias = (by == 0) ? b0 : (by == 1) ? b1 : (by == 2) ? b2 : b3;
        if (by < 3) ob = obf + by * 128; else of = of32;
    } else if (MODE == 1) {
        bias = b0 + by * 128;
        ob = obf + by * 128;
    } else {
        bias = b0;
        of = of32;
    }

    int g = lane >> 4, l15 = lane & 15;
#pragma unroll
    for (int nj = 0; nj < 4; ++nj) {
        int col = wc * 64 + nj * 16 + l15;
        float bb = bias[col];
#pragma unroll
        for (int mi = 0; mi < 4; ++mi) {
#pragma unroll
            for (int r = 0; r < 4; ++r) {
                int n = row0 + wr * 64 + mi * 16 + g * 4 + r;
                if (n < nrows) {
                    float v = acc[mi][nj][r] + bb;
                    if (MODE == 2) v += resid[(size_t)n * 128 + col];
                    if (MODE == 1 || MODE == 3) v = fmaxf(v, 0.f);
                    if (ob) ob[(size_t)n * 384 + col] = f2bf(v);
                    else    of[(size_t)n * 128 + col] = v;
                }
            }
        }
    }
}

// ---------------- per-node attention + LN1 (one wave per dst node) ----------------
// qkv: [N,384] bf16 (q|k|v). hmid holds skip (f32) on entry; overwritten with LN1 (f32).
// LN1 output additionally written as bf16 over the dead q-columns (own row only).
__global__ __launch_bounds__(256) void attn_kernel(
    u16* __restrict__ qkv,
    const u16* __restrict__ h_in, int ld_h,
    const int* __restrict__ offsets, const int* __restrict__ perm,
    const int* __restrict__ esrc, const float* __restrict__ eattr,
    const float* __restrict__ We_l,
    const float* __restrict__ g1, const float* __restrict__ b1,
    float* __restrict__ hmid, int N)
{
    int wid = threadIdx.x >> 6;
    int lane = threadIdx.x & 63;
    int n = blockIdx.x * 4 + wid;
    if (n >= N) return;
    int d0 = lane * 2;

    float we0[4], we1[4];
#pragma unroll
    for (int i = 0; i < 4; ++i) { we0[i] = We_l[i * H + d0]; we1[i] = We_l[i * H + d0 + 1]; }

    ushort2 qraw = *(const ushort2*)&qkv[(size_t)n * JK + d0];
    float q0 = bf2f(qraw.x), q1 = bf2f(qraw.y);
    float m = -INFINITY, ssum = 0.f, a0 = 0.f, a1 = 0.f;
    int e0 = offsets[n], e1 = offsets[n + 1];
    for (int j = e0; j < e1; ++j) {
        int e = perm[j];
        int s = esrc[e];
        const u16* srow = qkv + (size_t)s * JK;
        float4 ea = *(const float4*)&eattr[(size_t)e * 4];
        float eb0 = ea.x * we0[0] + ea.y * we0[1] + ea.z * we0[2] + ea.w * we0[3];
        float eb1 = ea.x * we1[0] + ea.y * we1[1] + ea.z * we1[2] + ea.w * we1[3];
        ushort2 kraw = *(const ushort2*)&srow[H + d0];
        ushort2 vraw = *(const ushort2*)&srow[2 * H + d0];
        float k0 = bf2f(kraw.x) + eb0, k1 = bf2f(kraw.y) + eb1;
        float v0 = bf2f(vraw.x) + eb0, v1 = bf2f(vraw.y) + eb1;
        float part = q0 * k0 + q1 * k1;
        part += __shfl_xor(part, 1, 16);
        part += __shfl_xor(part, 2, 16);
        part += __shfl_xor(part, 4, 16);
        part += __shfl_xor(part, 8, 16);
        float logit = part * ATT_SCALE;
        float mn = fmaxf(m, logit);
        float corr = __expf(m - mn);       // m = -inf first edge -> corr = 0
        float p = __expf(logit - mn);
        ssum = ssum * corr + p;
        a0 = a0 * corr + p * v0;
        a1 = a1 * corr + p * v1;
        m = mn;
    }
    float inv = 1.f / (ssum + 1e-16f);
    a0 *= inv; a1 *= inv;

    ushort2 hraw = *(const ushort2*)&h_in[(size_t)n * ld_h + d0];
    float2 sk = *(const float2*)&hmid[(size_t)n * H + d0];
    float t0 = bf2f(hraw.x) + a0 + sk.x;
    float t1 = bf2f(hraw.y) + a1 + sk.y;
    float sum = t0 + t1, sq = t0 * t0 + t1 * t1;
#pragma unroll
    for (int off = 32; off; off >>= 1) { sum += __shfl_xor(sum, off); sq += __shfl_xor(sq, off); }
    float mean = sum * (1.f / 128.f);
    float var = sq * (1.f / 128.f) - mean * mean;
    float rstd = rsqrtf(var + 1e-5f);
    float o0 = (t0 - mean) * rstd * g1[d0] + b1[d0];
    float o1 = (t1 - mean) * rstd * g1[d0 + 1] + b1[d0 + 1];
    *(float2*)&hmid[(size_t)n * H + d0] = make_float2(o0, o1);
    ushort2 ob; ob.x = f2bf(o0); ob.y = f2bf(o1);
    *(ushort2*)&qkv[(size_t)n * JK + d0] = ob;    // bf16 copy over dead q-cols
}

// ---------------- LayerNorm f32 in -> bf16 out (wave per row) ----------------
__global__ __launch_bounds__(256) void ln_kernel(const float* __restrict__ in,
                                                 const float* __restrict__ g,
                                                 const float* __restrict__ b,
                                                 u16* __restrict__ out, int ldo, int N) {
    int wid = threadIdx.x >> 6;
    int lane = threadIdx.x & 63;
    int n = blockIdx.x * 4 + wid;
    if (n >= N) return;
    int d0 = lane * 2;
    float2 t = *(const float2*)&in[(size_t)n * H + d0];
    float sum = t.x + t.y, sq = t.x * t.x + t.y * t.y;
#pragma unroll
    for (int off = 32; off; off >>= 1) { sum += __shfl_xor(sum, off); sq += __shfl_xor(sq, off); }
    float mean = sum * (1.f / 128.f);
    float var = sq * (1.f / 128.f) - mean * mean;
    float rstd = rsqrtf(var + 1e-5f);
    ushort2 s;
    s.x = f2bf((t.x - mean) * rstd * g[d0] + b[d0]);
    s.y = f2bf((t.y - mean) * rstd * g[d0 + 1] + b[d0 + 1]);
    *(ushort2*)&out[(size_t)n * ldo + d0] = s;
}

// ---------------- gate scalar: gate[n] = ghid[n,:] . Wg2 + bg2 ----------------
__global__ __launch_bounds__(256) void gate2_kernel(const float* __restrict__ ghid,
                                                    const float* __restrict__ Wg2,
                                                    const float* __restrict__ bg2,
                                                    float* __restrict__ gate, int N) {
    int wid = threadIdx.x >> 6;
    int lane = threadIdx.x & 63;
    int n = blockIdx.x * 4 + wid;
    if (n >= N) return;
    int d0 = lane * 2;
    float2 hv = *(const float2*)&ghid[(size_t)n * H + d0];
    float v = hv.x * Wg2[d0] + hv.y * Wg2[d0 + 1];
#pragma unroll
    for (int off = 32; off; off >>= 1) v += __shfl_xor(v, off);
    if (lane == 0) gate[n] = v + bg2[0];
}

// ---------------- per-graph softmax pooling ----------------
__global__ __launch_bounds__(256) void pool_kernel(const float* __restrict__ gate,
                                                   const u16* __restrict__ xc,
                                                   const int* __restrict__ gstart,
                                                   const float* __restrict__ u,
                                                   float* __restrict__ pooled, int G) {
    int g = blockIdx.x;
    int t = threadIdx.x;
    int s0 = gstart[g], s1 = gstart[g + 1];
    __shared__ float red[256];
    float mx = -INFINITY;
    for (int i = s0 + t; i < s1; i += 256) mx = fmaxf(mx, gate[i]);
    red[t] = mx; __syncthreads();
    for (int off = 128; off; off >>= 1) { if (t < off) red[t] = fmaxf(red[t], red[t + off]); __syncthreads(); }
    float gm = red[0]; __syncthreads();
    float sm = 0.f;
    for (int i = s0 + t; i < s1; i += 256) sm += __expf(gate[i] - gm);
    red[t] = sm; __syncthreads();
    for (int off = 128; off; off >>= 1) { if (t < off) red[t] += red[t + off]; __syncthreads(); }
    float inv = 1.f / (red[0] + 1e-16f);
    for (int d = t; d < JK; d += 256) {
        float acc = 0.f;
        for (int i = s0; i < s1; ++i)
            acc += __expf(gate[i] - gm) * bf2f(xc[(size_t)i * JK + d]);
        pooled[(size_t)g * (JK + 1) + d] = acc * inv;
    }
    if (t == 0) pooled[(size_t)g * (JK + 1) + JK] = u[g];
}

// ---------------- final MLP head ----------------
__global__ __launch_bounds__(128) void head_kernel(const float* __restrict__ pooled,
                                                   const float* __restrict__ Wh1,
                                                   const float* __restrict__ bh1,
                                                   const float* __restrict__ Wh2,
                                                   const float* __restrict__ bh2,
                                                   float* __restrict__ out, int G) {
    int g = blockIdx.x;
    int j = threadIdx.x;
    __shared__ float hid[128];
    float acc = bh1[j];
    const float* pr = pooled + (size_t)g * (JK + 1);
    for (int k = 0; k < JK + 1; ++k) acc = fmaf(pr[k], Wh1[(size_t)k * H + j], acc);
    hid[j] = fmaxf(acc, 0.f);
    __syncthreads();
    if (j < 3) {
        float o = bh2[j];
        for (int k = 0; k < H; ++k) o += hid[k] * Wh2[k * 3 + j];
        out[(size_t)g * 3 + j] = o;
    }
}

extern "C" void kernel_launch(void* const* d_in, const int* in_sizes, int n_in,
                              void* d_out, int out_size, void* d_ws, size_t ws_size,
                              hipStream_t stream) {
    const float* x     = (const float*)d_in[0];
    const int*   ei    = (const int*)d_in[1];
    const float* eattr = (const float*)d_in[2];
    const int*   batch = (const int*)d_in[3];
    const float* u     = (const float*)d_in[4];
    const float* Win   = (const float*)d_in[5];
    const float* b_in  = (const float*)d_in[6];
    const float* Wq    = (const float*)d_in[7];
    const float* bq    = (const float*)d_in[8];
    const float* Wk    = (const float*)d_in[9];
    const float* bk    = (const float*)d_in[10];
    const float* Wv    = (const float*)d_in[11];
    const float* bv    = (const float*)d_in[12];
    const float* We    = (const float*)d_in[13];
    const float* Wskip = (const float*)d_in[14];
    const float* bskip = (const float*)d_in[15];
    const float* ln1_g = (const float*)d_in[16];
    const float* ln1_b = (const float*)d_in[17];
    const float* Wf1   = (const float*)d_in[18];
    const float* bf1   = (const float*)d_in[19];
    const float* Wf2   = (const float*)d_in[20];
    const float* bf2   = (const float*)d_in[21];
    const float* ln2_g = (const float*)d_in[22];
    const float* ln2_b = (const float*)d_in[23];
    const float* Wg1   = (const float*)d_in[24];
    const float* bg1   = (const float*)d_in[25];
    const float* Wg2   = (const float*)d_in[26];
    const float* bg2   = (const float*)d_in[27];
    const float* Wh1   = (const float*)d_in[28];
    const float* bh1   = (const float*)d_in[29];
    const float* Wh2   = (const float*)d_in[30];
    const float* bh2   = (const float*)d_in[31];

    const int N = in_sizes[3];
    const int E = in_sizes[1] / 2;
    const int G = in_sizes[4];

    // workspace carve-up (256B aligned) — total ~212 MB
    char* p = (char*)d_ws;
    auto alloc = [&](size_t bytes) { char* r = p; p += (bytes + 255) & ~(size_t)255; return r; };
    int*   counts  = (int*)alloc((size_t)N * 4);
    int*   cursor  = (int*)alloc((size_t)N * 4);
    int*   offsets = (int*)alloc((size_t)(N + 1) * 4);
    int*   perm    = (int*)alloc((size_t)E * 4);
    int*   gstart  = (int*)alloc((size_t)(G + 1) * 4);
    int*   bsum    = (int*)alloc(128 * 4);
    int*   boffs   = (int*)alloc(128 * 4);
    float* gate    = (float*)alloc((size_t)N * 4);
    float* pooled  = (float*)alloc((size_t)G * (JK + 1) * 4);
    u16*   WT      = (u16*)alloc((size_t)442368 * 2);             // all weights bf16, transposed [Ncol][K]
    float* hmid    = (float*)alloc((size_t)N * H * 4);            // f32 [N,128]
    u16*   xc      = (u16*)alloc((size_t)N * JK * 2);             // bf16 [N,384]
    u16*   qkv     = (u16*)alloc((size_t)N * JK * 2);             // bf16 [N,384]; heavily reused
    float* ghid    = (float*)qkv;                                 // f32 [N,128] (fits in 76.8MB region)

    // WT layout offsets (elems)
    const int QKVS_OFF = 0;            // per layer: 512x128 (q|k|v|skip rows)
    const int F1_OFF   = 3 * 65536;    // per layer: 256x128
    const int F2_OFF   = F1_OFF + 3 * 32768;  // per layer: 128x256
    const int G1_OFF   = F2_OFF + 3 * 32768;  // 128x384

    hipMemsetAsync(counts, 0, (size_t)N * 4, stream);
    hipMemsetAsync(cursor, 0, (size_t)N * 4, stream);

    int eb = cdiv(E, 256);
    int nb = cdiv(N, 1024);
    hist_kernel<<<eb, 256, 0, stream>>>(ei, counts, E);
    scan1_kernel<<<nb, 256, 0, stream>>>(counts, offsets, bsum, N);
    scan2_kernel<<<1, 128, 0, stream>>>(bsum, boffs, offsets, nb, N);
    scan3_kernel<<<nb, 256, 0, stream>>>(offsets, boffs, N);
    scatter_kernel<<<eb, 256, 0, stream>>>(ei, offsets, cursor, perm, E);
    graph_bounds_kernel<<<cdiv(G + 1, 256), 256, 0, stream>>>(batch, gstart, N, G);

    // weight conversion (19 matrices)
    TA ta;
    for (int l = 0; l < 3; ++l) {
        ta.d[l * 4 + 0] = { Wq    + (size_t)l * 16384, QKVS_OFF + l * 65536 + 0,     128, 128 };
        ta.d[l * 4 + 1] = { Wk    + (size_t)l * 16384, QKVS_OFF + l * 65536 + 16384, 128, 128 };
        ta.d[l * 4 + 2] = { Wv    + (size_t)l * 16384, QKVS_OFF + l * 65536 + 32768, 128, 128 };
        ta.d[l * 4 + 3] = { Wskip + (size_t)l * 16384, QKVS_OFF + l * 65536 + 49152, 128, 128 };
        ta.d[12 + l]    = { Wf1   + (size_t)l * 32768, F1_OFF   + l * 32768,         128, 256 };
        ta.d[15 + l]    = { Wf2   + (size_t)l * 32768, F2_OFF   + l * 32768,         256, 128 };
    }
    ta.d[18] = { Wg1, G1_OFF, 384, 128 };
    dim3 wg(cdiv(49152, 256), 19);
    wconv_kernel<<<wg, 256, 0, stream>>>(ta, WT);

    input_proj_kernel<<<cdiv(N * 64, 256), 256, 0, stream>>>(x, Win, b_in, xc, JK, N);

    int gb = cdiv(N, 128);
    int nb4 = cdiv(N, 4);
    for (int l = 0; l < LAYERS; ++l) {
        const u16* hin = xc + (size_t)((l == 0) ? 0 : (l - 1) * H);
        // fused q|k|v|skip: q,k,v -> bf16 qkv; skip -> f32 hmid
        gemm_mfma<0><<<dim3(gb, 4), 256, 0, stream>>>(
            hin, JK, WT + QKVS_OFF + (size_t)l * 65536, 128,
            bq + l * H, bk + l * H, bv + l * H, bskip + l * H,
            nullptr, qkv, hmid, N);
        attn_kernel<<<nb4, 256, 0, stream>>>(qkv, hin, JK, offsets, perm, ei, eattr,
                                             We + (size_t)l * 4 * H, ln1_g + l * H, ln1_b + l * H,
                                             hmid, N);
        // FF1: A = ln1 bf16 (qkv cols 0..127) -> relu out bf16 at qkv cols 128..383
        gemm_mfma<1><<<dim3(gb, 2), 256, 0, stream>>>(
            qkv, JK, WT + F1_OFF + (size_t)l * 32768, 128,
            bf1 + (size_t)l * FFDIM, nullptr, nullptr, nullptr,
            nullptr, qkv + H, nullptr, N);
        // FF2: A = ff1 bf16 (qkv cols 128..383), resid = hmid f32, out hmid f32
        gemm_mfma<2><<<dim3(gb, 1), 256, 0, stream>>>(
            qkv + H, JK, WT + F2_OFF + (size_t)l * 32768, 256,
            bf2 + (size_t)l * H, nullptr, nullptr, nullptr,
            hmid, nullptr, hmid, N);
        ln_kernel<<<nb4, 256, 0, stream>>>(hmid, ln2_g + l * H, ln2_b + l * H,
                                           xc + (size_t)l * H, JK, N);
    }

    // gate hidden: A = xc bf16 K=384 -> relu f32 ghid
    gemm_mfma<3><<<dim3(gb, 1), 256, 0, stream>>>(
        xc, JK, WT + G1_OFF, JK,
        bg1, nullptr, nullptr, nullptr,
        nullptr, nullptr, ghid, N);
    gate2_kernel<<<nb4, 256, 0, stream>>>(ghid, Wg2, bg2, gate, N);
    pool_kernel<<<G, 256, 0, stream>>>(gate, xc, gstart, u, pooled, G);
    head_kernel<<<G, 128, 0, stream>>>(pooled, Wh1, bh1, Wh2, bh2, (float*)d_out, G);
}

// Round 4
// 1019.495 us; speedup vs baseline: 2.0888x; 1.0646x over previous
//
#include <hip/hip_runtime.h>
#include <math.h>

#define H 128
#define LAYERS 3
#define FFDIM 256
#define JK 384
#define ATT_SCALE 0.17677669529663687f

typedef unsigned short u16;
typedef __attribute__((ext_vector_type(4))) float f32x4;
typedef __attribute__((ext_vector_type(8))) short short8;
typedef __attribute__((ext_vector_type(8))) unsigned short ushort8v;

static inline int cdiv(int a, int b) { return (a + b - 1) / b; }

static __device__ __forceinline__ float bf2f(u16 u) {
    union { unsigned int i; float f; } v; v.i = ((unsigned int)u) << 16; return v.f;
}
static __device__ __forceinline__ u16 f2bf(float f) {
    union { float f; unsigned int i; } v; v.f = f;
    unsigned int r = v.i + 0x7FFFu + ((v.i >> 16) & 1u);
    return (u16)(r >> 16);
}

// ---------------- CSR build over dst ----------------
__global__ void hist_kernel(const int* __restrict__ ei, int* __restrict__ counts, int E) {
    int e = blockIdx.x * blockDim.x + threadIdx.x;
    if (e >= E) return;
    atomicAdd(&counts[ei[E + e]], 1);
}

// 3-phase scan: block-local scan -> block-sum scan -> add back
__global__ __launch_bounds__(256) void scan1_kernel(const int* __restrict__ counts,
                                                    int* __restrict__ offsets,
                                                    int* __restrict__ bsum, int N) {
    __shared__ int sh[256];
    int t = threadIdx.x;
    int base = blockIdx.x * 1024 + t * 4;
    int v0 = 0, v1 = 0, v2 = 0, v3 = 0;
    if (base + 3 < N) {
        int4 q = *(const int4*)&counts[base];
        v0 = q.x; v1 = q.y; v2 = q.z; v3 = q.w;
    } else {
        if (base < N) v0 = counts[base];
        if (base + 1 < N) v1 = counts[base + 1];
        if (base + 2 < N) v2 = counts[base + 2];
        if (base + 3 < N) v3 = counts[base + 3];
    }
    int ts = v0 + v1 + v2 + v3;
    sh[t] = ts; __syncthreads();
    for (int off = 1; off < 256; off <<= 1) {
        int x = (t >= off) ? sh[t - off] : 0;
        __syncthreads(); sh[t] += x; __syncthreads();
    }
    int excl = sh[t] - ts;
    if (base < N)     offsets[base]     = excl;
    if (base + 1 < N) offsets[base + 1] = excl + v0;
    if (base + 2 < N) offsets[base + 2] = excl + v0 + v1;
    if (base + 3 < N) offsets[base + 3] = excl + v0 + v1 + v2;
    if (t == 255) bsum[blockIdx.x] = sh[255];
}

__global__ __launch_bounds__(128) void scan2_kernel(const int* __restrict__ bsum,
                                                    int* __restrict__ boffs,
                                                    int* __restrict__ offsets, int nb, int N) {
    __shared__ int sh[128];
    int t = threadIdx.x;
    int s = (t < nb) ? bsum[t] : 0;
    sh[t] = s; __syncthreads();
    for (int off = 1; off < 128; off <<= 1) {
        int x = (t >= off) ? sh[t - off] : 0;
        __syncthreads(); sh[t] += x; __syncthreads();
    }
    if (t < nb) boffs[t] = sh[t] - s;
    if (t == 0) offsets[N] = sh[nb - 1];
}

__global__ __launch_bounds__(256) void scan3_kernel(int* __restrict__ offsets,
                                                    const int* __restrict__ boffs, int N) {
    int add = boffs[blockIdx.x];
    int base = blockIdx.x * 1024 + threadIdx.x * 4;
#pragma unroll
    for (int i = 0; i < 4; ++i)
        if (base + i < N) offsets[base + i] += add;
}

// scatter with payload: psrc = src node id, pe = edge_attr copy (permuted order)
__global__ void scatter_kernel(const int* __restrict__ ei, const float* __restrict__ eattr,
                               const int* __restrict__ offsets,
                               int* __restrict__ cursor, int* __restrict__ psrc,
                               float4* __restrict__ pe, int E) {
    int e = blockIdx.x * blockDim.x + threadIdx.x;
    if (e >= E) return;
    int d = ei[E + e];
    int pos = atomicAdd(&cursor[d], 1);
    int o = offsets[d] + pos;
    psrc[o] = ei[e];
    pe[o] = *(const float4*)&eattr[(size_t)e * 4];
}

__global__ void graph_bounds_kernel(const int* __restrict__ batch, int* __restrict__ gstart,
                                    int N, int G) {
    int g = blockIdx.x * blockDim.x + threadIdx.x;
    if (g > G) return;
    int lo = 0, hi = N;
    while (lo < hi) { int mid = (lo + hi) >> 1; if (batch[mid] < g) lo = mid + 1; else hi = mid; }
    gstart[g] = lo;
}

// ---------------- weight transpose+convert: WT[c*K+k] = bf16(W[k*N+c]) ----------------
struct TD { const float* src; int dstoff, K, N; };
struct TA { TD d[19]; };

__global__ __launch_bounds__(256) void wconv_kernel(TA a, u16* __restrict__ WT) {
    TD d = a.d[blockIdx.y];
    int i = blockIdx.x * 256 + threadIdx.x;
    int tot = d.K * d.N;
    if (i >= tot) return;
    int c = i / d.K, k = i - c * d.K;
    WT[d.dstoff + i] = f2bf(d.src[(size_t)k * d.N + c]);
}

// ---------------- input projection h0 = x @ Win + b -> bf16, strided into xc cols 0..127
__global__ __launch_bounds__(256) void input_proj_kernel(const float* __restrict__ x,
                                                         const float* __restrict__ Win,
                                                         const float* __restrict__ b_in,
                                                         u16* __restrict__ h, int ldh, int N) {
    int idx = blockIdx.x * 256 + threadIdx.x;     // N*64 threads, 2 cols each
    int n = idx >> 6, c = (idx & 63) * 2;
    if (n >= N) return;
    float4 xv = *(const float4*)&x[(size_t)n * 4];
    float o0 = b_in[c]     + xv.x * Win[c]     + xv.y * Win[H + c]     + xv.z * Win[2 * H + c]     + xv.w * Win[3 * H + c];
    float o1 = b_in[c + 1] + xv.x * Win[c + 1] + xv.y * Win[H + c + 1] + xv.z * Win[2 * H + c + 1] + xv.w * Win[3 * H + c + 1];
    ushort2 s; s.x = f2bf(o0); s.y = f2bf(o1);
    *(ushort2*)&h[(size_t)n * ldh + c] = s;
}

// ---------------- MFMA bf16 GEMM ----------------
// C[M,128] = A[M,K](bf16) @ WT[128,K]^T(bf16), XOR-swizzled LDS tiles, 4 waves x (64x64).
// 1D grid = gb*NBY, bijective XCD swizzle, by fastest (same-A blocks share an XCD's L2).
// MODE 0: qkv+skip  (NBY=4; by<3 -> bf16 out at obf+by*128 ld 384; by==3 -> f32 of32 ld 128)
// MODE 1: ff1       (NBY=2; bias b0+by*128; relu; bf16 out obf+by*128 ld 384)
// MODE 2: ff2       (resid f32 += ; f32 out ld 128)
// MODE 3: gate1     (fused: relu + dot(Wg2=b1) + bg2(=b2) -> of32 = gate[n])
__device__ __forceinline__ void stage_tile(const u16* __restrict__ g, int ld, int row0,
                                           int nrows, int kt, u16* __restrict__ sm, int t) {
#pragma unroll
    for (int i = 0; i < 4; ++i) {
        int f = i * 256 + t;              // chunk id 0..1023
        int row = f >> 3, ck = f & 7;
        int n = row0 + row; if (n >= nrows) n = nrows - 1;
        uint4 v = *(const uint4*)(g + (size_t)n * ld + kt + ck * 8);
        int sw = ck ^ (row & 7);
        *(uint4*)(sm + row * 64 + sw * 8) = v;
    }
}

template <int MODE, int NBY>
__global__ __launch_bounds__(256) void gemm_mfma(
    const u16* __restrict__ A, int lda,
    const u16* __restrict__ WT, int K,
    const float* __restrict__ b0, const float* __restrict__ b1,
    const float* __restrict__ b2, const float* __restrict__ b3,
    const float* __restrict__ resid,
    u16* __restrict__ obf, float* __restrict__ of32,
    int nrows)
{
    alignas(16) __shared__ u16 Asm[128 * 64];
    alignas(16) __shared__ u16 Bsm[128 * 64];
    int t = threadIdx.x;
    int lane = t & 63, wid = t >> 6;
    int wr = wid >> 1, wc = wid & 1;

    // bijective XCD swizzle: contiguous swz chunk per XCD; by fastest within swz
    int T = gridDim.x, id = blockIdx.x;
    int qd = T >> 3, rr = T & 7;
    int xcd = id & 7, pos = id >> 3;
    int swz = (xcd < rr ? xcd * (qd + 1) : rr * (qd + 1) + (xcd - rr) * qd) + pos;
    int by = swz & (NBY - 1);
    int row0 = (swz / NBY) * 128;

    const u16* WTb = WT + (size_t)by * 128 * K;

    f32x4 acc[4][4] = {};

    for (int kt = 0; kt < K; kt += 64) {
        stage_tile(A, lda, row0, nrows, kt, Asm, t);
        stage_tile(WTb, K, 0, 128, kt, Bsm, t);
        __syncthreads();
        int g = lane >> 4;
        int l15 = lane & 15;
#pragma unroll
        for (int kk = 0; kk < 2; ++kk) {
            int cb = kk * 4 + g;
            short8 af[4], bf[4];
#pragma unroll
            for (int mi = 0; mi < 4; ++mi) {
                int r = wr * 64 + mi * 16 + l15;
                af[mi] = *(const short8*)(Asm + r * 64 + ((cb ^ (r & 7)) * 8));
            }
#pragma unroll
            for (int nj = 0; nj < 4; ++nj) {
                int c = wc * 64 + nj * 16 + l15;
                bf[nj] = *(const short8*)(Bsm + c * 64 + ((cb ^ (c & 7)) * 8));
            }
#pragma unroll
            for (int mi = 0; mi < 4; ++mi)
#pragma unroll
                for (int nj = 0; nj < 4; ++nj)
                    acc[mi][nj] = __builtin_amdgcn_mfma_f32_16x16x32_bf16(af[mi], bf[nj], acc[mi][nj], 0, 0, 0);
        }
        __syncthreads();
    }

    int g = lane >> 4, l15 = lane & 15;

    if (MODE == 3) {
        // fused gate: gate[n] = relu(acc+bg1) . Wg2 + bg2
        float* gsum = (float*)Asm;          // reuse LDS (post-barrier)
        float part[4][4];
#pragma unroll
        for (int mi = 0; mi < 4; ++mi)
#pragma unroll
            for (int r = 0; r < 4; ++r) part[mi][r] = 0.f;
#pragma unroll
        for (int nj = 0; nj < 4; ++nj) {
            int col = wc * 64 + nj * 16 + l15;
            float bb = b0[col];
            float w2 = b1[col];
#pragma unroll
            for (int mi = 0; mi < 4; ++mi)
#pragma unroll
                for (int r = 0; r < 4; ++r) {
                    float v = fmaxf(acc[mi][nj][r] + bb, 0.f);
                    part[mi][r] = fmaf(v, w2, part[mi][r]);
                }
        }
#pragma unroll
        for (int off = 1; off <= 8; off <<= 1)
#pragma unroll
            for (int mi = 0; mi < 4; ++mi)
#pragma unroll
                for (int r = 0; r < 4; ++r) part[mi][r] += __shfl_xor(part[mi][r], off);
        if (wc == 0 && l15 == 0) {
#pragma unroll
            for (int mi = 0; mi < 4; ++mi)
#pragma unroll
                for (int r = 0; r < 4; ++r)
                    gsum[wr * 64 + mi * 16 + g * 4 + r] = part[mi][r];
        }
        __syncthreads();
        if (wc == 1 && l15 == 0) {
            float bg2v = b2[0];
#pragma unroll
            for (int mi = 0; mi < 4; ++mi)
#pragma unroll
                for (int r = 0; r < 4; ++r) {
                    int lr = wr * 64 + mi * 16 + g * 4 + r;
                    int n = row0 + lr;
                    if (n < nrows) of32[n] = part[mi][r] + gsum[lr] + bg2v;
                }
        }
        return;
    }

    const float* bias;
    u16* ob = nullptr; float* of = nullptr;
    if (MODE == 0) {
        bias = (by == 0) ? b0 : (by == 1) ? b1 : (by == 2) ? b2 : b3;
        if (by < 3) ob = obf + by * 128; else of = of32;
    } else if (MODE == 1) {
        bias = b0 + by * 128;
        ob = obf + by * 128;
    } else {
        bias = b0;
        of = of32;
    }

#pragma unroll
    for (int nj = 0; nj < 4; ++nj) {
        int col = wc * 64 + nj * 16 + l15;
        float bb = bias[col];
#pragma unroll
        for (int mi = 0; mi < 4; ++mi) {
#pragma unroll
            for (int r = 0; r < 4; ++r) {
                int n = row0 + wr * 64 + mi * 16 + g * 4 + r;
                if (n < nrows) {
                    float v = acc[mi][nj][r] + bb;
                    if (MODE == 2) v += resid[(size_t)n * 128 + col];
                    if (MODE == 1) v = fmaxf(v, 0.f);
                    if (ob) ob[(size_t)n * 384 + col] = f2bf(v);
                    else    of[(size_t)n * 128 + col] = v;
                }
            }
        }
    }
}

// ---------------- per-node attention + LN1 (one wave per dst node, 4 edges in flight) ----
// qkv: [N,384] bf16 (q|k|v). hmid holds skip (f32) on entry; overwritten with LN1 (f32).
// LN1 output additionally written as bf16 over the dead q-columns (own row only).
// Wave layout: slot = lane>>4 (edge slot, 4 concurrent edges), sub = lane&15, 8 dims/lane.
__global__ __launch_bounds__(256) void attn_kernel(
    u16* __restrict__ qkv,
    const u16* __restrict__ h_in, int ld_h,
    const int* __restrict__ offsets,
    const int* __restrict__ psrc, const float4* __restrict__ pe,
    const float* __restrict__ We_l,
    const float* __restrict__ g1, const float* __restrict__ b1,
    float* __restrict__ hmid, int N)
{
    int wid = threadIdx.x >> 6;
    int lane = threadIdx.x & 63;
    int n = blockIdx.x * 4 + wid;
    if (n >= N) return;
    int slot = lane >> 4, sub = lane & 15;
    int d0 = sub * 8;

    float we[4][8];
#pragma unroll
    for (int aa = 0; aa < 4; ++aa) {
        float4 w0 = *(const float4*)&We_l[aa * H + d0];
        float4 w1 = *(const float4*)&We_l[aa * H + d0 + 4];
        we[aa][0] = w0.x; we[aa][1] = w0.y; we[aa][2] = w0.z; we[aa][3] = w0.w;
        we[aa][4] = w1.x; we[aa][5] = w1.y; we[aa][6] = w1.z; we[aa][7] = w1.w;
    }

    ushort8v qraw = *(const ushort8v*)&qkv[(size_t)n * JK + d0];
    float qf[8];
#pragma unroll
    for (int i = 0; i < 8; ++i) qf[i] = bf2f(qraw[i]);

    float m = -INFINITY, ssum = 0.f;
    float a[8] = {0.f, 0.f, 0.f, 0.f, 0.f, 0.f, 0.f, 0.f};
    int e0 = offsets[n], e1 = offsets[n + 1];
    int nit = (e1 - e0 + 3) >> 2;
    for (int it = 0; it < nit; ++it) {
        int j = e0 + it * 4 + slot;
        bool act = j < e1;
        int jj = act ? j : e0;
        int s = psrc[jj];
        float4 ea = pe[jj];
        const u16* srow = qkv + (size_t)s * JK;
        ushort8v kraw = *(const ushort8v*)&srow[H + d0];
        ushort8v vraw = *(const ushort8v*)&srow[2 * H + d0];
        float part = 0.f, vv[8];
#pragma unroll
        for (int i = 0; i < 8; ++i) {
            float eb = ea.x * we[0][i] + ea.y * we[1][i] + ea.z * we[2][i] + ea.w * we[3][i];
            float kf = bf2f(kraw[i]) + eb;
            vv[i] = bf2f(vraw[i]) + eb;
            part = fmaf(qf[i], kf, part);
        }
        part += __shfl_xor(part, 1);       // reduce over the head's 4 lanes
        part += __shfl_xor(part, 2);
        if (act) {
            float logit = part * ATT_SCALE;
            float mn = fmaxf(m, logit);
            float corr = __expf(m - mn);   // m=-inf first edge -> corr=0
            float p = __expf(logit - mn);
            ssum = ssum * corr + p;
#pragma unroll
            for (int i = 0; i < 8; ++i) a[i] = a[i] * corr + p * vv[i];
            m = mn;
        }
    }
    // flash-merge the 4 slots (butterfly over lane bits 4,5)
#pragma unroll
    for (int D = 16; D <= 32; D <<= 1) {
        float mo = __shfl_xor(m, D);
        float so = __shfl_xor(ssum, D);
        float ao[8];
#pragma unroll
        for (int i = 0; i < 8; ++i) ao[i] = __shfl_xor(a[i], D);
        float m2 = fmaxf(m, mo);
        float c1 = (m > -INFINITY) ? __expf(m - m2) : 0.f;
        float c2 = (mo > -INFINITY) ? __expf(mo - m2) : 0.f;
        ssum = ssum * c1 + so * c2;
#pragma unroll
        for (int i = 0; i < 8; ++i) a[i] = a[i] * c1 + ao[i] * c2;
        m = m2;
    }
    float inv = 1.f / (ssum + 1e-16f);

    ushort8v hraw = *(const ushort8v*)&h_in[(size_t)n * ld_h + d0];
    float4 sk0 = *(const float4*)&hmid[(size_t)n * H + d0];
    float4 sk1 = *(const float4*)&hmid[(size_t)n * H + d0 + 4];
    float skf[8] = {sk0.x, sk0.y, sk0.z, sk0.w, sk1.x, sk1.y, sk1.z, sk1.w};
    float tv[8], sum = 0.f, sq = 0.f;
#pragma unroll
    for (int i = 0; i < 8; ++i) {
        tv[i] = bf2f(hraw[i]) + a[i] * inv + skf[i];
        sum += tv[i]; sq += tv[i] * tv[i];
    }
#pragma unroll
    for (int off = 32; off; off >>= 1) { sum += __shfl_xor(sum, off); sq += __shfl_xor(sq, off); }
    float mean = sum * (1.f / 512.f);      // each dim counted 4x (once per slot)
    float var = sq * (1.f / 512.f) - mean * mean;
    float rstd = rsqrtf(var + 1e-5f);
    if (slot == 0) {
        float4 ga = *(const float4*)&g1[d0];
        float4 gb = *(const float4*)&g1[d0 + 4];
        float4 ba = *(const float4*)&b1[d0];
        float4 bb = *(const float4*)&b1[d0 + 4];
        float gg[8] = {ga.x, ga.y, ga.z, ga.w, gb.x, gb.y, gb.z, gb.w};
        float bbv[8] = {ba.x, ba.y, ba.z, ba.w, bb.x, bb.y, bb.z, bb.w};
        float o[8];
        ushort8v obv;
#pragma unroll
        for (int i = 0; i < 8; ++i) {
            o[i] = (tv[i] - mean) * rstd * gg[i] + bbv[i];
            obv[i] = f2bf(o[i]);
        }
        *(float4*)&hmid[(size_t)n * H + d0]     = make_float4(o[0], o[1], o[2], o[3]);
        *(float4*)&hmid[(size_t)n * H + d0 + 4] = make_float4(o[4], o[5], o[6], o[7]);
        *(ushort8v*)&qkv[(size_t)n * JK + d0] = obv;   // bf16 LN1 over dead q-cols
    }
}

// ---------------- LayerNorm f32 in -> bf16 out (wave per row) ----------------
__global__ __launch_bounds__(256) void ln_kernel(const float* __restrict__ in,
                                                 const float* __restrict__ g,
                                                 const float* __restrict__ b,
                                                 u16* __restrict__ out, int ldo, int N) {
    int wid = threadIdx.x >> 6;
    int lane = threadIdx.x & 63;
    int n = blockIdx.x * 4 + wid;
    if (n >= N) return;
    int d0 = lane * 2;
    float2 t = *(const float2*)&in[(size_t)n * H + d0];
    float sum = t.x + t.y, sq = t.x * t.x + t.y * t.y;
#pragma unroll
    for (int off = 32; off; off >>= 1) { sum += __shfl_xor(sum, off); sq += __shfl_xor(sq, off); }
    float mean = sum * (1.f / 128.f);
    float var = sq * (1.f / 128.f) - mean * mean;
    float rstd = rsqrtf(var + 1e-5f);
    ushort2 s;
    s.x = f2bf((t.x - mean) * rstd * g[d0] + b[d0]);
    s.y = f2bf((t.y - mean) * rstd * g[d0 + 1] + b[d0 + 1]);
    *(ushort2*)&out[(size_t)n * ldo + d0] = s;
}

// ---------------- per-graph softmax pooling ----------------
__global__ __launch_bounds__(256) void pool_kernel(const float* __restrict__ gate,
                                                   const u16* __restrict__ xc,
                                                   const int* __restrict__ gstart,
                                                   const float* __restrict__ u,
                                                   float* __restrict__ pooled, int G) {
    int g = blockIdx.x;
    int t = threadIdx.x;
    int s0 = gstart[g], s1 = gstart[g + 1];
    __shared__ float red[256];
    float mx = -INFINITY;
    for (int i = s0 + t; i < s1; i += 256) mx = fmaxf(mx, gate[i]);
    red[t] = mx; __syncthreads();
    for (int off = 128; off; off >>= 1) { if (t < off) red[t] = fmaxf(red[t], red[t + off]); __syncthreads(); }
    float gm = red[0]; __syncthreads();
    float sm = 0.f;
    for (int i = s0 + t; i < s1; i += 256) sm += __expf(gate[i] - gm);
    red[t] = sm; __syncthreads();
    for (int off = 128; off; off >>= 1) { if (t < off) red[t] += red[t + off]; __syncthreads(); }
    float inv = 1.f / (red[0] + 1e-16f);
    for (int d = t; d < JK; d += 256) {
        float acc = 0.f;
        for (int i = s0; i < s1; ++i)
            acc += __expf(gate[i] - gm) * bf2f(xc[(size_t)i * JK + d]);
        pooled[(size_t)g * (JK + 1) + d] = acc * inv;
    }
    if (t == 0) pooled[(size_t)g * (JK + 1) + JK] = u[g];
}

// ---------------- final MLP head ----------------
__global__ __launch_bounds__(128) void head_kernel(const float* __restrict__ pooled,
                                                   const float* __restrict__ Wh1,
                                                   const float* __restrict__ bh1,
                                                   const float* __restrict__ Wh2,
                                                   const float* __restrict__ bh2,
                                                   float* __restrict__ out, int G) {
    int g = blockIdx.x;
    int j = threadIdx.x;
    __shared__ float hid[128];
    float acc = bh1[j];
    const float* pr = pooled + (size_t)g * (JK + 1);
    for (int k = 0; k < JK + 1; ++k) acc = fmaf(pr[k], Wh1[(size_t)k * H + j], acc);
    hid[j] = fmaxf(acc, 0.f);
    __syncthreads();
    if (j < 3) {
        float o = bh2[j];
        for (int k = 0; k < H; ++k) o += hid[k] * Wh2[k * 3 + j];
        out[(size_t)g * 3 + j] = o;
    }
}

extern "C" void kernel_launch(void* const* d_in, const int* in_sizes, int n_in,
                              void* d_out, int out_size, void* d_ws, size_t ws_size,
                              hipStream_t stream) {
    const float* x     = (const float*)d_in[0];
    const int*   ei    = (const int*)d_in[1];
    const float* eattr = (const float*)d_in[2];
    const int*   batch = (const int*)d_in[3];
    const float* u     = (const float*)d_in[4];
    const float* Win   = (const float*)d_in[5];
    const float* b_in  = (const float*)d_in[6];
    const float* Wq    = (const float*)d_in[7];
    const float* bq    = (const float*)d_in[8];
    const float* Wk    = (const float*)d_in[9];
    const float* bk    = (const float*)d_in[10];
    const float* Wv    = (const float*)d_in[11];
    const float* bv    = (const float*)d_in[12];
    const float* We    = (const float*)d_in[13];
    const float* Wskip = (const float*)d_in[14];
    const float* bskip = (const float*)d_in[15];
    const float* ln1_g = (const float*)d_in[16];
    const float* ln1_b = (const float*)d_in[17];
    const float* Wf1   = (const float*)d_in[18];
    const float* bf1   = (const float*)d_in[19];
    const float* Wf2   = (const float*)d_in[20];
    const float* bf2   = (const float*)d_in[21];
    const float* ln2_g = (const float*)d_in[22];
    const float* ln2_b = (const float*)d_in[23];
    const float* Wg1   = (const float*)d_in[24];
    const float* bg1   = (const float*)d_in[25];
    const float* Wg2   = (const float*)d_in[26];
    const float* bg2   = (const float*)d_in[27];
    const float* Wh1   = (const float*)d_in[28];
    const float* bh1   = (const float*)d_in[29];
    const float* Wh2   = (const float*)d_in[30];
    const float* bh2   = (const float*)d_in[31];

    const int N = in_sizes[3];
    const int E = in_sizes[1] / 2;
    const int G = in_sizes[4];

    // workspace carve-up (256B aligned) — total ~215 MB
    char* p = (char*)d_ws;
    auto alloc = [&](size_t bytes) { char* r = p; p += (bytes + 255) & ~(size_t)255; return r; };
    int*    counts  = (int*)alloc((size_t)N * 4);
    int*    cursor  = (int*)alloc((size_t)N * 4);
    int*    offsets = (int*)alloc((size_t)(N + 1) * 4);
    int*    psrc    = (int*)alloc((size_t)E * 4);
    float4* pe      = (float4*)alloc((size_t)E * 16);
    int*    gstart  = (int*)alloc((size_t)(G + 1) * 4);
    int*    bsum    = (int*)alloc(128 * 4);
    int*    boffs   = (int*)alloc(128 * 4);
    float*  gate    = (float*)alloc((size_t)N * 4);
    float*  pooled  = (float*)alloc((size_t)G * (JK + 1) * 4);
    u16*    WT      = (u16*)alloc((size_t)442368 * 2);            // all weights bf16, transposed [Ncol][K]
    float*  hmid    = (float*)alloc((size_t)N * H * 4);           // f32 [N,128]
    u16*    xc      = (u16*)alloc((size_t)N * JK * 2);            // bf16 [N,384]
    u16*    qkv     = (u16*)alloc((size_t)N * JK * 2);            // bf16 [N,384]; heavily reused

    // WT layout offsets (elems)
    const int QKVS_OFF = 0;            // per layer: 512x128 (q|k|v|skip rows)
    const int F1_OFF   = 3 * 65536;    // per layer: 256x128
    const int F2_OFF   = F1_OFF + 3 * 32768;  // per layer: 128x256
    const int G1_OFF   = F2_OFF + 3 * 32768;  // 128x384

    hipMemsetAsync(counts, 0, (size_t)N * 4, stream);
    hipMemsetAsync(cursor, 0, (size_t)N * 4, stream);

    int eb = cdiv(E, 256);
    int nb = cdiv(N, 1024);
    hist_kernel<<<eb, 256, 0, stream>>>(ei, counts, E);
    scan1_kernel<<<nb, 256, 0, stream>>>(counts, offsets, bsum, N);
    scan2_kernel<<<1, 128, 0, stream>>>(bsum, boffs, offsets, nb, N);
    scan3_kernel<<<nb, 256, 0, stream>>>(offsets, boffs, N);
    scatter_kernel<<<eb, 256, 0, stream>>>(ei, eattr, offsets, cursor, psrc, pe, E);
    graph_bounds_kernel<<<cdiv(G + 1, 256), 256, 0, stream>>>(batch, gstart, N, G);

    // weight conversion (19 matrices)
    TA ta;
    for (int l = 0; l < 3; ++l) {
        ta.d[l * 4 + 0] = { Wq    + (size_t)l * 16384, QKVS_OFF + l * 65536 + 0,     128, 128 };
        ta.d[l * 4 + 1] = { Wk    + (size_t)l * 16384, QKVS_OFF + l * 65536 + 16384, 128, 128 };
        ta.d[l * 4 + 2] = { Wv    + (size_t)l * 16384, QKVS_OFF + l * 65536 + 32768, 128, 128 };
        ta.d[l * 4 + 3] = { Wskip + (size_t)l * 16384, QKVS_OFF + l * 65536 + 49152, 128, 128 };
        ta.d[12 + l]    = { Wf1   + (size_t)l * 32768, F1_OFF   + l * 32768,         128, 256 };
        ta.d[15 + l]    = { Wf2   + (size_t)l * 32768, F2_OFF   + l * 32768,         256, 128 };
    }
    ta.d[18] = { Wg1, G1_OFF, 384, 128 };
    dim3 wg(cdiv(49152, 256), 19);
    wconv_kernel<<<wg, 256, 0, stream>>>(ta, WT);

    input_proj_kernel<<<cdiv(N * 64, 256), 256, 0, stream>>>(x, Win, b_in, xc, JK, N);

    int gb = cdiv(N, 128);
    int nb4 = cdiv(N, 4);
    for (int l = 0; l < LAYERS; ++l) {
        const u16* hin = xc + (size_t)((l == 0) ? 0 : (l - 1) * H);
        // fused q|k|v|skip: q,k,v -> bf16 qkv; skip -> f32 hmid
        gemm_mfma<0, 4><<<gb * 4, 256, 0, stream>>>(
            hin, JK, WT + QKVS_OFF + (size_t)l * 65536, 128,
            bq + l * H, bk + l * H, bv + l * H, bskip + l * H,
            nullptr, qkv, hmid, N);
        attn_kernel<<<nb4, 256, 0, stream>>>(qkv, hin, JK, offsets, psrc, pe,
                                             We + (size_t)l * 4 * H, ln1_g + l * H, ln1_b + l * H,
                                             hmid, N);
        // FF1: A = ln1 bf16 (qkv cols 0..127) -> relu out bf16 at qkv cols 128..383
        gemm_mfma<1, 2><<<gb * 2, 256, 0, stream>>>(
            qkv, JK, WT + F1_OFF + (size_t)l * 32768, 128,
            bf1 + (size_t)l * FFDIM, nullptr, nullptr, nullptr,
            nullptr, qkv + H, nullptr, N);
        // FF2: A = ff1 bf16 (qkv cols 128..383), resid = hmid f32, out hmid f32
        gemm_mfma<2, 1><<<gb, 256, 0, stream>>>(
            qkv + H, JK, WT + F2_OFF + (size_t)l * 32768, 256,
            bf2 + (size_t)l * H, nullptr, nullptr, nullptr,
            hmid, nullptr, hmid, N);
        ln_kernel<<<nb4, 256, 0, stream>>>(hmid, ln2_g + l * H, ln2_b + l * H,
                                           xc + (size_t)l * H, JK, N);
    }

    // gate: A = xc bf16 K=384, fused relu+dot(Wg2)+bg2 -> gate[n]
    gemm_mfma<3, 1><<<gb, 256, 0, stream>>>(
        xc, JK, WT + G1_OFF, JK,
        bg1, Wg2, bg2, nullptr,
        nullptr, nullptr, gate, N);
    pool_kernel<<<G, 256, 0, stream>>>(gate, xc, gstart, u, pooled, G);
    head_kernel<<<G, 128, 0, stream>>>(pooled, Wh1, bh1, Wh2, bh2, (float*)d_out, G);
}

// Round 6
// 885.376 us; speedup vs baseline: 2.4052x; 1.1515x over previous
//
#include <hip/hip_runtime.h>
#include <math.h>

#define H 128
#define LAYERS 3
#define FFDIM 256
#define JK 384
#define ATT_SCALE 0.17677669529663687f

typedef unsigned short u16;
typedef __attribute__((ext_vector_type(4))) float f32x4;
typedef __attribute__((ext_vector_type(8))) short short8;
typedef __attribute__((ext_vector_type(8))) unsigned short ushort8v;

static inline int cdiv(int a, int b) { return (a + b - 1) / b; }

static __device__ __forceinline__ float bf2f(u16 u) {
    union { unsigned int i; float f; } v; v.i = ((unsigned int)u) << 16; return v.f;
}
static __device__ __forceinline__ u16 f2bf(float f) {
    union { float f; unsigned int i; } v; v.f = f;
    unsigned int r = v.i + 0x7FFFu + ((v.i >> 16) & 1u);
    return (u16)(r >> 16);
}

// ---------------- CSR build over dst ----------------
__global__ void hist_kernel(const int* __restrict__ ei, int* __restrict__ counts, int E) {
    int e = blockIdx.x * blockDim.x + threadIdx.x;
    if (e >= E) return;
    atomicAdd(&counts[ei[E + e]], 1);
}

// 3-phase scan: block-local scan -> block-sum scan -> add back
__global__ __launch_bounds__(256) void scan1_kernel(const int* __restrict__ counts,
                                                    int* __restrict__ offsets,
                                                    int* __restrict__ bsum, int N) {
    __shared__ int sh[256];
    int t = threadIdx.x;
    int base = blockIdx.x * 1024 + t * 4;
    int v0 = 0, v1 = 0, v2 = 0, v3 = 0;
    if (base + 3 < N) {
        int4 q = *(const int4*)&counts[base];
        v0 = q.x; v1 = q.y; v2 = q.z; v3 = q.w;
    } else {
        if (base < N) v0 = counts[base];
        if (base + 1 < N) v1 = counts[base + 1];
        if (base + 2 < N) v2 = counts[base + 2];
        if (base + 3 < N) v3 = counts[base + 3];
    }
    int ts = v0 + v1 + v2 + v3;
    sh[t] = ts; __syncthreads();
    for (int off = 1; off < 256; off <<= 1) {
        int x = (t >= off) ? sh[t - off] : 0;
        __syncthreads(); sh[t] += x; __syncthreads();
    }
    int excl = sh[t] - ts;
    if (base < N)     offsets[base]     = excl;
    if (base + 1 < N) offsets[base + 1] = excl + v0;
    if (base + 2 < N) offsets[base + 2] = excl + v0 + v1;
    if (base + 3 < N) offsets[base + 3] = excl + v0 + v1 + v2;
    if (t == 255) bsum[blockIdx.x] = sh[255];
}

__global__ __launch_bounds__(128) void scan2_kernel(const int* __restrict__ bsum,
                                                    int* __restrict__ boffs,
                                                    int* __restrict__ offsets, int nb, int N) {
    __shared__ int sh[128];
    int t = threadIdx.x;
    int s = (t < nb) ? bsum[t] : 0;
    sh[t] = s; __syncthreads();
    for (int off = 1; off < 128; off <<= 1) {
        int x = (t >= off) ? sh[t - off] : 0;
        __syncthreads(); sh[t] += x; __syncthreads();
    }
    if (t < nb) boffs[t] = sh[t] - s;
    if (t == 0) offsets[N] = sh[nb - 1];
}

__global__ __launch_bounds__(256) void scan3_kernel(int* __restrict__ offsets,
                                                    const int* __restrict__ boffs, int N) {
    int add = boffs[blockIdx.x];
    int base = blockIdx.x * 1024 + threadIdx.x * 4;
#pragma unroll
    for (int i = 0; i < 4; ++i)
        if (base + i < N) offsets[base + i] += add;
}

// scatter with payload: psrc = src node id, pe = edge_attr copy (permuted order)
__global__ void scatter_kernel(const int* __restrict__ ei, const float* __restrict__ eattr,
                               const int* __restrict__ offsets,
                               int* __restrict__ cursor, int* __restrict__ psrc,
                               float4* __restrict__ pe, int E) {
    int e = blockIdx.x * blockDim.x + threadIdx.x;
    if (e >= E) return;
    int d = ei[E + e];
    int pos = atomicAdd(&cursor[d], 1);
    int o = offsets[d] + pos;
    psrc[o] = ei[e];
    pe[o] = *(const float4*)&eattr[(size_t)e * 4];
}

__global__ void graph_bounds_kernel(const int* __restrict__ batch, int* __restrict__ gstart,
                                    int N, int G) {
    int g = blockIdx.x * blockDim.x + threadIdx.x;
    if (g > G) return;
    int lo = 0, hi = N;
    while (lo < hi) { int mid = (lo + hi) >> 1; if (batch[mid] < g) lo = mid + 1; else hi = mid; }
    gstart[g] = lo;
}

// ---------------- weight transpose+convert: WT[c*K+k] = bf16(W[k*N+c]) ----------------
struct TD { const float* src; int dstoff, K, N; };
struct TA { TD d[19]; };

__global__ __launch_bounds__(256) void wconv_kernel(TA a, u16* __restrict__ WT) {
    TD d = a.d[blockIdx.y];
    int i = blockIdx.x * 256 + threadIdx.x;
    int tot = d.K * d.N;
    if (i >= tot) return;
    int c = i / d.K, k = i - c * d.K;
    WT[d.dstoff + i] = f2bf(d.src[(size_t)k * d.N + c]);
}

// ---------------- input projection h0 = x @ Win + b -> bf16, strided into xc cols 0..127
__global__ __launch_bounds__(256) void input_proj_kernel(const float* __restrict__ x,
                                                         const float* __restrict__ Win,
                                                         const float* __restrict__ b_in,
                                                         u16* __restrict__ h, int ldh, int N) {
    int idx = blockIdx.x * 256 + threadIdx.x;     // N*64 threads, 2 cols each
    int n = idx >> 6, c = (idx & 63) * 2;
    if (n >= N) return;
    float4 xv = *(const float4*)&x[(size_t)n * 4];
    float o0 = b_in[c]     + xv.x * Win[c]     + xv.y * Win[H + c]     + xv.z * Win[2 * H + c]     + xv.w * Win[3 * H + c];
    float o1 = b_in[c + 1] + xv.x * Win[c + 1] + xv.y * Win[H + c + 1] + xv.z * Win[2 * H + c + 1] + xv.w * Win[3 * H + c + 1];
    ushort2 s; s.x = f2bf(o0); s.y = f2bf(o1);
    *(ushort2*)&h[(size_t)n * ldh + c] = s;
}

// ---------------- MFMA bf16 GEMM ----------------
// C[M,128] = A[M,K](bf16) @ WT[128,K]^T(bf16), XOR-swizzled LDS tiles, 4 waves x (64x64).
// 1D grid = gb*NBY, bijective XCD swizzle, by fastest (same-A blocks share an XCD's L2).
// MODE 0: qkv+skip  (NBY=4; by<3 -> bf16 out at obf+by*128 ld 384; by==3 -> f32 of32 ld 128)
// MODE 1: ff1       (NBY=2; bias b0+by*128; relu; bf16 out obf+by*128 ld 384)
// MODE 2: ff2       (resid f32 += ; f32 out ld 128)
// MODE 3: gate1     (fused: relu + dot(Wg2=b1) + bg2(=b2) -> of32 = gate[n])
__device__ __forceinline__ void stage_tile(const u16* __restrict__ g, int ld, int row0,
                                           int nrows, int kt, u16* __restrict__ sm, int t) {
#pragma unroll
    for (int i = 0; i < 4; ++i) {
        int f = i * 256 + t;              // chunk id 0..1023
        int row = f >> 3, ck = f & 7;
        int n = row0 + row; if (n >= nrows) n = nrows - 1;
        uint4 v = *(const uint4*)(g + (size_t)n * ld + kt + ck * 8);
        int sw = ck ^ (row & 7);
        *(uint4*)(sm + row * 64 + sw * 8) = v;
    }
}

template <int MODE, int NBY>
__global__ __launch_bounds__(256) void gemm_mfma(
    const u16* __restrict__ A, int lda,
    const u16* __restrict__ WT, int K,
    const float* __restrict__ b0, const float* __restrict__ b1,
    const float* __restrict__ b2, const float* __restrict__ b3,
    const float* __restrict__ resid,
    u16* __restrict__ obf, float* __restrict__ of32,
    int nrows)
{
    alignas(16) __shared__ u16 Asm[128 * 64];
    alignas(16) __shared__ u16 Bsm[128 * 64];
    int t = threadIdx.x;
    int lane = t & 63, wid = t >> 6;
    int wr = wid >> 1, wc = wid & 1;

    // bijective XCD swizzle: contiguous swz chunk per XCD; by fastest within swz
    int T = gridDim.x, id = blockIdx.x;
    int qd = T >> 3, rr = T & 7;
    int xcd = id & 7, pos = id >> 3;
    int swz = (xcd < rr ? xcd * (qd + 1) : rr * (qd + 1) + (xcd - rr) * qd) + pos;
    int by = swz & (NBY - 1);
    int row0 = (swz / NBY) * 128;

    const u16* WTb = WT + (size_t)by * 128 * K;

    f32x4 acc[4][4] = {};

    for (int kt = 0; kt < K; kt += 64) {
        stage_tile(A, lda, row0, nrows, kt, Asm, t);
        stage_tile(WTb, K, 0, 128, kt, Bsm, t);
        __syncthreads();
        int g = lane >> 4;
        int l15 = lane & 15;
#pragma unroll
        for (int kk = 0; kk < 2; ++kk) {
            int cb = kk * 4 + g;
            short8 af[4], bf[4];
#pragma unroll
            for (int mi = 0; mi < 4; ++mi) {
                int r = wr * 64 + mi * 16 + l15;
                af[mi] = *(const short8*)(Asm + r * 64 + ((cb ^ (r & 7)) * 8));
            }
#pragma unroll
            for (int nj = 0; nj < 4; ++nj) {
                int c = wc * 64 + nj * 16 + l15;
                bf[nj] = *(const short8*)(Bsm + c * 64 + ((cb ^ (c & 7)) * 8));
            }
#pragma unroll
            for (int mi = 0; mi < 4; ++mi)
#pragma unroll
                for (int nj = 0; nj < 4; ++nj)
                    acc[mi][nj] = __builtin_amdgcn_mfma_f32_16x16x32_bf16(af[mi], bf[nj], acc[mi][nj], 0, 0, 0);
        }
        __syncthreads();
    }

    int g = lane >> 4, l15 = lane & 15;

    if (MODE == 3) {
        // fused gate: gate[n] = relu(acc+bg1) . Wg2 + bg2
        float* gsum = (float*)Asm;          // reuse LDS (post-barrier)
        float part[4][4];
#pragma unroll
        for (int mi = 0; mi < 4; ++mi)
#pragma unroll
            for (int r = 0; r < 4; ++r) part[mi][r] = 0.f;
#pragma unroll
        for (int nj = 0; nj < 4; ++nj) {
            int col = wc * 64 + nj * 16 + l15;
            float bb = b0[col];
            float w2 = b1[col];
#pragma unroll
            for (int mi = 0; mi < 4; ++mi)
#pragma unroll
                for (int r = 0; r < 4; ++r) {
                    float v = fmaxf(acc[mi][nj][r] + bb, 0.f);
                    part[mi][r] = fmaf(v, w2, part[mi][r]);
                }
        }
#pragma unroll
        for (int off = 1; off <= 8; off <<= 1)
#pragma unroll
            for (int mi = 0; mi < 4; ++mi)
#pragma unroll
                for (int r = 0; r < 4; ++r) part[mi][r] += __shfl_xor(part[mi][r], off);
        if (wc == 0 && l15 == 0) {
#pragma unroll
            for (int mi = 0; mi < 4; ++mi)
#pragma unroll
                for (int r = 0; r < 4; ++r)
                    gsum[wr * 64 + mi * 16 + g * 4 + r] = part[mi][r];
        }
        __syncthreads();
        if (wc == 1 && l15 == 0) {
            float bg2v = b2[0];
#pragma unroll
            for (int mi = 0; mi < 4; ++mi)
#pragma unroll
                for (int r = 0; r < 4; ++r) {
                    int lr = wr * 64 + mi * 16 + g * 4 + r;
                    int n = row0 + lr;
                    if (n < nrows) of32[n] = part[mi][r] + gsum[lr] + bg2v;
                }
        }
        return;
    }

    const float* bias;
    u16* ob = nullptr; float* of = nullptr;
    if (MODE == 0) {
        bias = (by == 0) ? b0 : (by == 1) ? b1 : (by == 2) ? b2 : b3;
        if (by < 3) ob = obf + by * 128; else of = of32;
    } else if (MODE == 1) {
        bias = b0 + by * 128;
        ob = obf + by * 128;
    } else {
        bias = b0;
        of = of32;
    }

#pragma unroll
    for (int nj = 0; nj < 4; ++nj) {
        int col = wc * 64 + nj * 16 + l15;
        float bb = bias[col];
#pragma unroll
        for (int mi = 0; mi < 4; ++mi) {
#pragma unroll
            for (int r = 0; r < 4; ++r) {
                int n = row0 + wr * 64 + mi * 16 + g * 4 + r;
                if (n < nrows) {
                    float v = acc[mi][nj][r] + bb;
                    if (MODE == 2) v += resid[(size_t)n * 128 + col];
                    if (MODE == 1) v = fmaxf(v, 0.f);
                    if (ob) ob[(size_t)n * 384 + col] = f2bf(v);
                    else    of[(size_t)n * 128 + col] = v;
                }
            }
        }
    }
}

// ---------------- per-node attention + LN1 (16 lanes per node, 4 nodes per wave) --------
// qkv: [N,384] bf16 (q|k|v). hmid holds skip (f32) on entry; overwritten with LN1 (f32).
// LN1 output additionally written as bf16 over the dead q-columns (own row only).
// Each 16-lane group owns one node. MULTI-HEAD: 4 heads x 32 dims; each head = 4 lanes
// (4 lanes x 8 dims). QK dot reduces over xor 1,2 ONLY (per-head); per-lane m/ssum then
// track that lane's head softmax. LN reduces over all 16 lanes (factor 1/128).
__global__ __launch_bounds__(256) void attn_kernel(
    u16* __restrict__ qkv,
    const u16* __restrict__ h_in, int ld_h,
    const int* __restrict__ offsets,
    const int* __restrict__ psrc, const float4* __restrict__ pe,
    const float* __restrict__ We_l,
    const float* __restrict__ g1, const float* __restrict__ b1,
    float* __restrict__ hmid, int N)
{
    int tid = threadIdx.x;
    int grp = tid >> 4;                    // 16 nodes per block
    int sub = tid & 15;
    int n = blockIdx.x * 16 + grp;
    if (n >= N) return;
    int d0 = sub * 8;

    float we[4][8];
#pragma unroll
    for (int aa = 0; aa < 4; ++aa) {
        float4 w0 = *(const float4*)&We_l[aa * H + d0];
        float4 w1 = *(const float4*)&We_l[aa * H + d0 + 4];
        we[aa][0] = w0.x; we[aa][1] = w0.y; we[aa][2] = w0.z; we[aa][3] = w0.w;
        we[aa][4] = w1.x; we[aa][5] = w1.y; we[aa][6] = w1.z; we[aa][7] = w1.w;
    }

    ushort8v qraw = *(const ushort8v*)&qkv[(size_t)n * JK + d0];
    float qf[8];
#pragma unroll
    for (int i = 0; i < 8; ++i) qf[i] = bf2f(qraw[i]);

    float m = -INFINITY, ssum = 0.f;
    float a[8] = {0.f, 0.f, 0.f, 0.f, 0.f, 0.f, 0.f, 0.f};
    int e0 = offsets[n], e1 = offsets[n + 1];
    for (int j = e0; j < e1; ++j) {
        int s = psrc[j];
        float4 ea = pe[j];
        const u16* srow = qkv + (size_t)s * JK;
        ushort8v kraw = *(const ushort8v*)&srow[H + d0];
        ushort8v vraw = *(const ushort8v*)&srow[2 * H + d0];
        float part = 0.f, vv[8];
#pragma unroll
        for (int i = 0; i < 8; ++i) {
            float eb = ea.x * we[0][i] + ea.y * we[1][i] + ea.z * we[2][i] + ea.w * we[3][i];
            float kf = bf2f(kraw[i]) + eb;
            vv[i] = bf2f(vraw[i]) + eb;
            part = fmaf(qf[i], kf, part);
        }
        part += __shfl_xor(part, 1);       // per-head reduce over the head's 4 lanes
        part += __shfl_xor(part, 2);       // (NOT 4/8 -- heads are independent!)
        float logit = part * ATT_SCALE;
        float mn = fmaxf(m, logit);
        float corr = __expf(m - mn);       // m=-inf first edge -> corr=0
        float p = __expf(logit - mn);
        ssum = ssum * corr + p;
#pragma unroll
        for (int i = 0; i < 8; ++i) a[i] = a[i] * corr + p * vv[i];
        m = mn;
    }
    float inv = 1.f / (ssum + 1e-16f);

    ushort8v hraw = *(const ushort8v*)&h_in[(size_t)n * ld_h + d0];
    float4 sk0 = *(const float4*)&hmid[(size_t)n * H + d0];
    float4 sk1 = *(const float4*)&hmid[(size_t)n * H + d0 + 4];
    float skf[8] = {sk0.x, sk0.y, sk0.z, sk0.w, sk1.x, sk1.y, sk1.z, sk1.w};
    float tv[8], sum = 0.f, sq = 0.f;
#pragma unroll
    for (int i = 0; i < 8; ++i) {
        tv[i] = bf2f(hraw[i]) + a[i] * inv + skf[i];
        sum += tv[i]; sq += tv[i] * tv[i];
    }
    // LN reduce over the 16-lane group (128 dims, each counted once)
#pragma unroll
    for (int off = 1; off <= 8; off <<= 1) { sum += __shfl_xor(sum, off); sq += __shfl_xor(sq, off); }
    float mean = sum * (1.f / 128.f);
    float var = sq * (1.f / 128.f) - mean * mean;
    float rstd = rsqrtf(var + 1e-5f);
    float4 ga = *(const float4*)&g1[d0];
    float4 gb = *(const float4*)&g1[d0 + 4];
    float4 ba = *(const float4*)&b1[d0];
    float4 bb = *(const float4*)&b1[d0 + 4];
    float gg[8] = {ga.x, ga.y, ga.z, ga.w, gb.x, gb.y, gb.z, gb.w};
    float bbv[8] = {ba.x, ba.y, ba.z, ba.w, bb.x, bb.y, bb.z, bb.w};
    float o[8];
    ushort8v obv;
#pragma unroll
    for (int i = 0; i < 8; ++i) {
        o[i] = (tv[i] - mean) * rstd * gg[i] + bbv[i];
        obv[i] = f2bf(o[i]);
    }
    *(float4*)&hmid[(size_t)n * H + d0]     = make_float4(o[0], o[1], o[2], o[3]);
    *(float4*)&hmid[(size_t)n * H + d0 + 4] = make_float4(o[4], o[5], o[6], o[7]);
    *(ushort8v*)&qkv[(size_t)n * JK + d0] = obv;   // bf16 LN1 over dead q-cols
}

// ---------------- LayerNorm f32 in -> bf16 out (wave per row) ----------------
__global__ __launch_bounds__(256) void ln_kernel(const float* __restrict__ in,
                                                 const float* __restrict__ g,
                                                 const float* __restrict__ b,
                                                 u16* __restrict__ out, int ldo, int N) {
    int wid = threadIdx.x >> 6;
    int lane = threadIdx.x & 63;
    int n = blockIdx.x * 4 + wid;
    if (n >= N) return;
    int d0 = lane * 2;
    float2 t = *(const float2*)&in[(size_t)n * H + d0];
    float sum = t.x + t.y, sq = t.x * t.x + t.y * t.y;
#pragma unroll
    for (int off = 32; off; off >>= 1) { sum += __shfl_xor(sum, off); sq += __shfl_xor(sq, off); }
    float mean = sum * (1.f / 128.f);
    float var = sq * (1.f / 128.f) - mean * mean;
    float rstd = rsqrtf(var + 1e-5f);
    ushort2 s;
    s.x = f2bf((t.x - mean) * rstd * g[d0] + b[d0]);
    s.y = f2bf((t.y - mean) * rstd * g[d0 + 1] + b[d0 + 1]);
    *(ushort2*)&out[(size_t)n * ldo + d0] = s;
}

// ---------------- per-graph softmax pooling (weights cached in LDS) ----------------
#define PCH 512
__global__ __launch_bounds__(256) void pool_kernel(const float* __restrict__ gate,
                                                   const u16* __restrict__ xc,
                                                   const int* __restrict__ gstart,
                                                   const float* __restrict__ u,
                                                   float* __restrict__ pooled, int G) {
    int g = blockIdx.x;
    int t = threadIdx.x;
    int s0 = gstart[g], s1 = gstart[g + 1];
    __shared__ float red[256];
    __shared__ float w[PCH];
    float mx = -INFINITY;
    for (int i = s0 + t; i < s1; i += 256) mx = fmaxf(mx, gate[i]);
    red[t] = mx; __syncthreads();
    for (int off = 128; off; off >>= 1) { if (t < off) red[t] = fmaxf(red[t], red[t + off]); __syncthreads(); }
    float gm = red[0]; __syncthreads();
    float sm = 0.f;
    for (int i = s0 + t; i < s1; i += 256) sm += __expf(gate[i] - gm);
    red[t] = sm; __syncthreads();
    for (int off = 128; off; off >>= 1) { if (t < off) red[t] += red[t + off]; __syncthreads(); }
    float inv = 1.f / (red[0] + 1e-16f);
    float acc0 = 0.f, acc1 = 0.f;
    for (int base = s0; base < s1; base += PCH) {
        int cnt = min(PCH, s1 - base);
        __syncthreads();
        for (int i = t; i < cnt; i += 256) w[i] = __expf(gate[base + i] - gm) * inv;
        __syncthreads();
        for (int c = 0; c < cnt; ++c) {
            const u16* row = xc + (size_t)(base + c) * JK;
            float wc = w[c];
            acc0 = fmaf(wc, bf2f(row[t]), acc0);
            if (t < 128) acc1 = fmaf(wc, bf2f(row[t + 256]), acc1);
        }
    }
    pooled[(size_t)g * (JK + 1) + t] = acc0;
    if (t < 128) pooled[(size_t)g * (JK + 1) + t + 256] = acc1;
    if (t == 0) pooled[(size_t)g * (JK + 1) + JK] = u[g];
}

// ---------------- final MLP head ----------------
__global__ __launch_bounds__(128) void head_kernel(const float* __restrict__ pooled,
                                                   const float* __restrict__ Wh1,
                                                   const float* __restrict__ bh1,
                                                   const float* __restrict__ Wh2,
                                                   const float* __restrict__ bh2,
                                                   float* __restrict__ out, int G) {
    int g = blockIdx.x;
    int j = threadIdx.x;
    __shared__ float hid[128];
    float acc = bh1[j];
    const float* pr = pooled + (size_t)g * (JK + 1);
    for (int k = 0; k < JK + 1; ++k) acc = fmaf(pr[k], Wh1[(size_t)k * H + j], acc);
    hid[j] = fmaxf(acc, 0.f);
    __syncthreads();
    if (j < 3) {
        float o = bh2[j];
        for (int k = 0; k < H; ++k) o += hid[k] * Wh2[k * 3 + j];
        out[(size_t)g * 3 + j] = o;
    }
}

extern "C" void kernel_launch(void* const* d_in, const int* in_sizes, int n_in,
                              void* d_out, int out_size, void* d_ws, size_t ws_size,
                              hipStream_t stream) {
    const float* x     = (const float*)d_in[0];
    const int*   ei    = (const int*)d_in[1];
    const float* eattr = (const float*)d_in[2];
    const int*   batch = (const int*)d_in[3];
    const float* u     = (const float*)d_in[4];
    const float* Win   = (const float*)d_in[5];
    const float* b_in  = (const float*)d_in[6];
    const float* Wq    = (const float*)d_in[7];
    const float* bq    = (const float*)d_in[8];
    const float* Wk    = (const float*)d_in[9];
    const float* bk    = (const float*)d_in[10];
    const float* Wv    = (const float*)d_in[11];
    const float* bv    = (const float*)d_in[12];
    const float* We    = (const float*)d_in[13];
    const float* Wskip = (const float*)d_in[14];
    const float* bskip = (const float*)d_in[15];
    const float* ln1_g = (const float*)d_in[16];
    const float* ln1_b = (const float*)d_in[17];
    const float* Wf1   = (const float*)d_in[18];
    const float* bf1   = (const float*)d_in[19];
    const float* Wf2   = (const float*)d_in[20];
    const float* bf2   = (const float*)d_in[21];
    const float* ln2_g = (const float*)d_in[22];
    const float* ln2_b = (const float*)d_in[23];
    const float* Wg1   = (const float*)d_in[24];
    const float* bg1   = (const float*)d_in[25];
    const float* Wg2   = (const float*)d_in[26];
    const float* bg2   = (const float*)d_in[27];
    const float* Wh1   = (const float*)d_in[28];
    const float* bh1   = (const float*)d_in[29];
    const float* Wh2   = (const float*)d_in[30];
    const float* bh2   = (const float*)d_in[31];

    const int N = in_sizes[3];
    const int E = in_sizes[1] / 2;
    const int G = in_sizes[4];

    // workspace carve-up (256B aligned) — total ~215 MB
    char* p = (char*)d_ws;
    auto alloc = [&](size_t bytes) { char* r = p; p += (bytes + 255) & ~(size_t)255; return r; };
    int*    counts  = (int*)alloc((size_t)N * 4);
    int*    cursor  = (int*)alloc((size_t)N * 4);
    int*    offsets = (int*)alloc((size_t)(N + 1) * 4);
    int*    psrc    = (int*)alloc((size_t)E * 4);
    float4* pe      = (float4*)alloc((size_t)E * 16);
    int*    gstart  = (int*)alloc((size_t)(G + 1) * 4);
    int*    bsum    = (int*)alloc(128 * 4);
    int*    boffs   = (int*)alloc(128 * 4);
    float*  gate    = (float*)alloc((size_t)N * 4);
    float*  pooled  = (float*)alloc((size_t)G * (JK + 1) * 4);
    u16*    WT      = (u16*)alloc((size_t)442368 * 2);            // all weights bf16, transposed [Ncol][K]
    float*  hmid    = (float*)alloc((size_t)N * H * 4);           // f32 [N,128]
    u16*    xc      = (u16*)alloc((size_t)N * JK * 2);            // bf16 [N,384]
    u16*    qkv     = (u16*)alloc((size_t)N * JK * 2);            // bf16 [N,384]; heavily reused

    // WT layout offsets (elems)
    const int QKVS_OFF = 0;            // per layer: 512x128 (q|k|v|skip rows)
    const int F1_OFF   = 3 * 65536;    // per layer: 256x128
    const int F2_OFF   = F1_OFF + 3 * 32768;  // per layer: 128x256
    const int G1_OFF   = F2_OFF + 3 * 32768;  // 128x384

    hipMemsetAsync(counts, 0, (size_t)N * 4, stream);
    hipMemsetAsync(cursor, 0, (size_t)N * 4, stream);

    int eb = cdiv(E, 256);
    int nb = cdiv(N, 1024);
    hist_kernel<<<eb, 256, 0, stream>>>(ei, counts, E);
    scan1_kernel<<<nb, 256, 0, stream>>>(counts, offsets, bsum, N);
    scan2_kernel<<<1, 128, 0, stream>>>(bsum, boffs, offsets, nb, N);
    scan3_kernel<<<nb, 256, 0, stream>>>(offsets, boffs, N);
    scatter_kernel<<<eb, 256, 0, stream>>>(ei, eattr, offsets, cursor, psrc, pe, E);
    graph_bounds_kernel<<<cdiv(G + 1, 256), 256, 0, stream>>>(batch, gstart, N, G);

    // weight conversion (19 matrices)
    TA ta;
    for (int l = 0; l < 3; ++l) {
        ta.d[l * 4 + 0] = { Wq    + (size_t)l * 16384, QKVS_OFF + l * 65536 + 0,     128, 128 };
        ta.d[l * 4 + 1] = { Wk    + (size_t)l * 16384, QKVS_OFF + l * 65536 + 16384, 128, 128 };
        ta.d[l * 4 + 2] = { Wv    + (size_t)l * 16384, QKVS_OFF + l * 65536 + 32768, 128, 128 };
        ta.d[l * 4 + 3] = { Wskip + (size_t)l * 16384, QKVS_OFF + l * 65536 + 49152, 128, 128 };
        ta.d[12 + l]    = { Wf1   + (size_t)l * 32768, F1_OFF   + l * 32768,         128, 256 };
        ta.d[15 + l]    = { Wf2   + (size_t)l * 32768, F2_OFF   + l * 32768,         256, 128 };
    }
    ta.d[18] = { Wg1, G1_OFF, 384, 128 };
    dim3 wg(cdiv(49152, 256), 19);
    wconv_kernel<<<wg, 256, 0, stream>>>(ta, WT);

    input_proj_kernel<<<cdiv(N * 64, 256), 256, 0, stream>>>(x, Win, b_in, xc, JK, N);

    int gb = cdiv(N, 128);
    int nb16 = cdiv(N, 16);
    int nb4 = cdiv(N, 4);
    for (int l = 0; l < LAYERS; ++l) {
        const u16* hin = xc + (size_t)((l == 0) ? 0 : (l - 1) * H);
        // fused q|k|v|skip: q,k,v -> bf16 qkv; skip -> f32 hmid
        gemm_mfma<0, 4><<<gb * 4, 256, 0, stream>>>(
            hin, JK, WT + QKVS_OFF + (size_t)l * 65536, 128,
            bq + l * H, bk + l * H, bv + l * H, bskip + l * H,
            nullptr, qkv, hmid, N);
        attn_kernel<<<nb16, 256, 0, stream>>>(qkv, hin, JK, offsets, psrc, pe,
                                              We + (size_t)l * 4 * H, ln1_g + l * H, ln1_b + l * H,
                                              hmid, N);
        // FF1: A = ln1 bf16 (qkv cols 0..127) -> relu out bf16 at qkv cols 128..383
        gemm_mfma<1, 2><<<gb * 2, 256, 0, stream>>>(
            qkv, JK, WT + F1_OFF + (size_t)l * 32768, 128,
            bf1 + (size_t)l * FFDIM, nullptr, nullptr, nullptr,
            nullptr, qkv + H, nullptr, N);
        // FF2: A = ff1 bf16 (qkv cols 128..383), resid = hmid f32, out hmid f32
        gemm_mfma<2, 1><<<gb, 256, 0, stream>>>(
            qkv + H, JK, WT + F2_OFF + (size_t)l * 32768, 256,
            bf2 + (size_t)l * H, nullptr, nullptr, nullptr,
            hmid, nullptr, hmid, N);
        ln_kernel<<<nb4, 256, 0, stream>>>(hmid, ln2_g + l * H, ln2_b + l * H,
                                           xc + (size_t)l * H, JK, N);
    }

    // gate: A = xc bf16 K=384, fused relu+dot(Wg2)+bg2 -> gate[n]
    gemm_mfma<3, 1><<<gb, 256, 0, stream>>>(
        xc, JK, WT + G1_OFF, JK,
        bg1, Wg2, bg2, nullptr,
        nullptr, nullptr, gate, N);
    pool_kernel<<<G, 256, 0, stream>>>(gate, xc, gstart, u, pooled, G);
    head_kernel<<<G, 128, 0, stream>>>(pooled, Wh1, bh1, Wh2, bh2, (float*)d_out, G);
}

// Round 7
// 724.825 us; speedup vs baseline: 2.9379x; 1.2215x over previous
//
#include <hip/hip_runtime.h>
#include <math.h>

#define H 128
#define LAYERS 3
#define FFDIM 256
#define JK 384
#define ATT_SCALE 0.17677669529663687f

typedef unsigned short u16;
typedef __attribute__((ext_vector_type(4))) float f32x4;
typedef __attribute__((ext_vector_type(8))) short short8;
typedef __attribute__((ext_vector_type(8))) unsigned short ushort8v;

static inline int cdiv(int a, int b) { return (a + b - 1) / b; }

static __device__ __forceinline__ float bf2f(u16 u) {
    union { unsigned int i; float f; } v; v.i = ((unsigned int)u) << 16; return v.f;
}
static __device__ __forceinline__ u16 f2bf(float f) {
    union { float f; unsigned int i; } v; v.f = f;
    unsigned int r = v.i + 0x7FFFu + ((v.i >> 16) & 1u);
    return (u16)(r >> 16);
}

// ---------------- CSR build over dst ----------------
__global__ void hist_kernel(const int* __restrict__ ei, int* __restrict__ counts, int E) {
    int e = blockIdx.x * blockDim.x + threadIdx.x;
    if (e >= E) return;
    atomicAdd(&counts[ei[E + e]], 1);
}

// 3-phase scan: block-local scan -> block-sum scan -> add back
__global__ __launch_bounds__(256) void scan1_kernel(const int* __restrict__ counts,
                                                    int* __restrict__ offsets,
                                                    int* __restrict__ bsum, int N) {
    __shared__ int sh[256];
    int t = threadIdx.x;
    int base = blockIdx.x * 1024 + t * 4;
    int v0 = 0, v1 = 0, v2 = 0, v3 = 0;
    if (base + 3 < N) {
        int4 q = *(const int4*)&counts[base];
        v0 = q.x; v1 = q.y; v2 = q.z; v3 = q.w;
    } else {
        if (base < N) v0 = counts[base];
        if (base + 1 < N) v1 = counts[base + 1];
        if (base + 2 < N) v2 = counts[base + 2];
        if (base + 3 < N) v3 = counts[base + 3];
    }
    int ts = v0 + v1 + v2 + v3;
    sh[t] = ts; __syncthreads();
    for (int off = 1; off < 256; off <<= 1) {
        int x = (t >= off) ? sh[t - off] : 0;
        __syncthreads(); sh[t] += x; __syncthreads();
    }
    int excl = sh[t] - ts;
    if (base < N)     offsets[base]     = excl;
    if (base + 1 < N) offsets[base + 1] = excl + v0;
    if (base + 2 < N) offsets[base + 2] = excl + v0 + v1;
    if (base + 3 < N) offsets[base + 3] = excl + v0 + v1 + v2;
    if (t == 255) bsum[blockIdx.x] = sh[255];
}

__global__ __launch_bounds__(128) void scan2_kernel(const int* __restrict__ bsum,
                                                    int* __restrict__ boffs,
                                                    int* __restrict__ offsets, int nb, int N) {
    __shared__ int sh[128];
    int t = threadIdx.x;
    int s = (t < nb) ? bsum[t] : 0;
    sh[t] = s; __syncthreads();
    for (int off = 1; off < 128; off <<= 1) {
        int x = (t >= off) ? sh[t - off] : 0;
        __syncthreads(); sh[t] += x; __syncthreads();
    }
    if (t < nb) boffs[t] = sh[t] - s;
    if (t == 0) offsets[N] = sh[nb - 1];
}

__global__ __launch_bounds__(256) void scan3_kernel(int* __restrict__ offsets,
                                                    const int* __restrict__ boffs, int N) {
    int add = boffs[blockIdx.x];
    int base = blockIdx.x * 1024 + threadIdx.x * 4;
#pragma unroll
    for (int i = 0; i < 4; ++i)
        if (base + i < N) offsets[base + i] += add;
}

// scatter with payload: psrc = src node id, pe = edge_attr copy (permuted order)
__global__ void scatter_kernel(const int* __restrict__ ei, const float* __restrict__ eattr,
                               const int* __restrict__ offsets,
                               int* __restrict__ cursor, int* __restrict__ psrc,
                               float4* __restrict__ pe, int E) {
    int e = blockIdx.x * blockDim.x + threadIdx.x;
    if (e >= E) return;
    int d = ei[E + e];
    int pos = atomicAdd(&cursor[d], 1);
    int o = offsets[d] + pos;
    psrc[o] = ei[e];
    pe[o] = *(const float4*)&eattr[(size_t)e * 4];
}

__global__ void graph_bounds_kernel(const int* __restrict__ batch, int* __restrict__ gstart,
                                    int N, int G) {
    int g = blockIdx.x * blockDim.x + threadIdx.x;
    if (g > G) return;
    int lo = 0, hi = N;
    while (lo < hi) { int mid = (lo + hi) >> 1; if (batch[mid] < g) lo = mid + 1; else hi = mid; }
    gstart[g] = lo;
}

// ---------------- weight transpose+convert: WT[c*K+k] = bf16(W[k*N+c]) ----------------
struct TD { const float* src; int dstoff, K, N; };
struct TA { TD d[19]; };

__global__ __launch_bounds__(256) void wconv_kernel(TA a, u16* __restrict__ WT) {
    TD d = a.d[blockIdx.y];
    int i = blockIdx.x * 256 + threadIdx.x;
    int tot = d.K * d.N;
    if (i >= tot) return;
    int c = i / d.K, k = i - c * d.K;
    WT[d.dstoff + i] = f2bf(d.src[(size_t)k * d.N + c]);
}

// ---------------- input projection h0 = x @ Win + b -> bf16, strided into xc cols 0..127
__global__ __launch_bounds__(256) void input_proj_kernel(const float* __restrict__ x,
                                                         const float* __restrict__ Win,
                                                         const float* __restrict__ b_in,
                                                         u16* __restrict__ h, int ldh, int N) {
    int idx = blockIdx.x * 256 + threadIdx.x;     // N*64 threads, 2 cols each
    int n = idx >> 6, c = (idx & 63) * 2;
    if (n >= N) return;
    float4 xv = *(const float4*)&x[(size_t)n * 4];
    float o0 = b_in[c]     + xv.x * Win[c]     + xv.y * Win[H + c]     + xv.z * Win[2 * H + c]     + xv.w * Win[3 * H + c];
    float o1 = b_in[c + 1] + xv.x * Win[c + 1] + xv.y * Win[H + c + 1] + xv.z * Win[2 * H + c + 1] + xv.w * Win[3 * H + c + 1];
    ushort2 s; s.x = f2bf(o0); s.y = f2bf(o1);
    *(ushort2*)&h[(size_t)n * ldh + c] = s;
}

// ---------------- MFMA bf16 GEMM ----------------
// C[M,128] = A[M,K](bf16) @ WT[128,K]^T(bf16), XOR-swizzled LDS tiles, 4 waves x (64x64).
// 1D grid = gb*NBY, bijective XCD swizzle, by fastest (same-A blocks share an XCD's L2).
// Epilogue: LDS-staged (2 phases of 64 rows) -> fully coalesced 256B/512B row-segment writes.
// MODE 0: qkv+skip  (NBY=4; by<3 -> bf16 out at obf+by*128 ld 384; by==3 -> f32 of32 ld 128)
// MODE 1: ff1       (NBY=2; bias b0+by*128; relu; bf16 out obf+by*128 ld 384)
// MODE 2: ff2       (resid f32 += at copy-out; f32 out ld 128)
// MODE 3: gate1     (fused: relu + dot(Wg2=b1) + bg2(=b2) -> of32 = gate[n])
__device__ __forceinline__ void stage_tile(const u16* __restrict__ g, int ld, int row0,
                                           int nrows, int kt, u16* __restrict__ sm, int t) {
#pragma unroll
    for (int i = 0; i < 4; ++i) {
        int f = i * 256 + t;              // chunk id 0..1023
        int row = f >> 3, ck = f & 7;
        int n = row0 + row; if (n >= nrows) n = nrows - 1;
        uint4 v = *(const uint4*)(g + (size_t)n * ld + kt + ck * 8);
        int sw = ck ^ (row & 7);
        *(uint4*)(sm + row * 64 + sw * 8) = v;
    }
}

template <int MODE, int NBY>
__global__ __launch_bounds__(256) void gemm_mfma(
    const u16* __restrict__ A, int lda,
    const u16* __restrict__ WT, int K,
    const float* __restrict__ b0, const float* __restrict__ b1,
    const float* __restrict__ b2, const float* __restrict__ b3,
    const float* __restrict__ resid,
    u16* __restrict__ obf, float* __restrict__ of32,
    int nrows)
{
    alignas(16) __shared__ char smemraw[33792];   // A/B tiles (32KB) then reused as f32 stage[64][132]
    u16* Asm = (u16*)smemraw;
    u16* Bsm = (u16*)(smemraw + 16384);
    float* stage = (float*)smemraw;
    int t = threadIdx.x;
    int lane = t & 63, wid = t >> 6;
    int wr = wid >> 1, wc = wid & 1;

    // bijective XCD swizzle: contiguous swz chunk per XCD; by fastest within swz
    int T = gridDim.x, id = blockIdx.x;
    int qd = T >> 3, rr = T & 7;
    int xcd = id & 7, pos = id >> 3;
    int swz = (xcd < rr ? xcd * (qd + 1) : rr * (qd + 1) + (xcd - rr) * qd) + pos;
    int by = swz & (NBY - 1);
    int row0 = (swz / NBY) * 128;

    const u16* WTb = WT + (size_t)by * 128 * K;

    f32x4 acc[4][4] = {};

    for (int kt = 0; kt < K; kt += 64) {
        stage_tile(A, lda, row0, nrows, kt, Asm, t);
        stage_tile(WTb, K, 0, 128, kt, Bsm, t);
        __syncthreads();
        int g = lane >> 4;
        int l15 = lane & 15;
#pragma unroll
        for (int kk = 0; kk < 2; ++kk) {
            int cb = kk * 4 + g;
            short8 af[4], bf[4];
#pragma unroll
            for (int mi = 0; mi < 4; ++mi) {
                int r = wr * 64 + mi * 16 + l15;
                af[mi] = *(const short8*)(Asm + r * 64 + ((cb ^ (r & 7)) * 8));
            }
#pragma unroll
            for (int nj = 0; nj < 4; ++nj) {
                int c = wc * 64 + nj * 16 + l15;
                bf[nj] = *(const short8*)(Bsm + c * 64 + ((cb ^ (c & 7)) * 8));
            }
#pragma unroll
            for (int mi = 0; mi < 4; ++mi)
#pragma unroll
                for (int nj = 0; nj < 4; ++nj)
                    acc[mi][nj] = __builtin_amdgcn_mfma_f32_16x16x32_bf16(af[mi], bf[nj], acc[mi][nj], 0, 0, 0);
        }
        __syncthreads();
    }

    int g = lane >> 4, l15 = lane & 15;

    if (MODE == 3) {
        // fused gate: gate[n] = relu(acc+bg1) . Wg2 + bg2
        float* gsum = (float*)Asm;          // reuse LDS (post-barrier)
        float part[4][4];
#pragma unroll
        for (int mi = 0; mi < 4; ++mi)
#pragma unroll
            for (int r = 0; r < 4; ++r) part[mi][r] = 0.f;
#pragma unroll
        for (int nj = 0; nj < 4; ++nj) {
            int col = wc * 64 + nj * 16 + l15;
            float bb = b0[col];
            float w2 = b1[col];
#pragma unroll
            for (int mi = 0; mi < 4; ++mi)
#pragma unroll
                for (int r = 0; r < 4; ++r) {
                    float v = fmaxf(acc[mi][nj][r] + bb, 0.f);
                    part[mi][r] = fmaf(v, w2, part[mi][r]);
                }
        }
#pragma unroll
        for (int off = 1; off <= 8; off <<= 1)
#pragma unroll
            for (int mi = 0; mi < 4; ++mi)
#pragma unroll
                for (int r = 0; r < 4; ++r) part[mi][r] += __shfl_xor(part[mi][r], off);
        if (wc == 0 && l15 == 0) {
#pragma unroll
            for (int mi = 0; mi < 4; ++mi)
#pragma unroll
                for (int r = 0; r < 4; ++r)
                    gsum[wr * 64 + mi * 16 + g * 4 + r] = part[mi][r];
        }
        __syncthreads();
        if (wc == 1 && l15 == 0) {
            float bg2v = b2[0];
#pragma unroll
            for (int mi = 0; mi < 4; ++mi)
#pragma unroll
                for (int r = 0; r < 4; ++r) {
                    int lr = wr * 64 + mi * 16 + g * 4 + r;
                    int n = row0 + lr;
                    if (n < nrows) of32[n] = part[mi][r] + gsum[lr] + bg2v;
                }
        }
        return;
    }

    const float* bias;
    u16* ob = nullptr; float* of = nullptr;
    if (MODE == 0) {
        bias = (by == 0) ? b0 : (by == 1) ? b1 : (by == 2) ? b2 : b3;
        if (by < 3) ob = obf + by * 128; else of = of32;
    } else if (MODE == 1) {
        bias = b0 + by * 128;
        ob = obf + by * 128;
    } else {
        bias = b0;
        of = of32;
    }

    // staged epilogue: 2 phases x 64 rows via LDS, fully coalesced global writes
#pragma unroll
    for (int p = 0; p < 2; ++p) {
        if (wr == p) {
#pragma unroll
            for (int nj = 0; nj < 4; ++nj) {
                int col = wc * 64 + nj * 16 + l15;
                float bb = bias[col];
#pragma unroll
                for (int mi = 0; mi < 4; ++mi)
#pragma unroll
                    for (int r = 0; r < 4; ++r) {
                        float v = acc[mi][nj][r] + bb;
                        if (MODE == 1) v = fmaxf(v, 0.f);
                        stage[(mi * 16 + g * 4 + r) * 132 + col] = v;
                    }
            }
        }
        __syncthreads();
        if (ob) {
            // bf16 out, ld 384: 16 lanes x ushort8 = 256B contiguous per row segment
#pragma unroll
            for (int it = 0; it < 4; ++it) {
                int lr = it * 16 + (t >> 4);
                int gr = row0 + p * 64 + lr;
                if (gr < nrows) {
                    int c8 = l15 * 8;
                    ushort8v o;
#pragma unroll
                    for (int i = 0; i < 8; ++i) o[i] = f2bf(stage[lr * 132 + c8 + i]);
                    *(ushort8v*)&ob[(size_t)gr * 384 + c8] = o;
                }
            }
        } else {
            // f32 out, ld 128: 32 lanes x float4 = 512B contiguous per row
            int l31 = t & 31;
#pragma unroll
            for (int it = 0; it < 8; ++it) {
                int lr = it * 8 + (t >> 5);
                int gr = row0 + p * 64 + lr;
                if (gr < nrows) {
                    int c4 = l31 * 4;
                    float4 v = *(float4*)&stage[lr * 132 + c4];
                    if (MODE == 2) {
                        float4 rv = *(const float4*)&resid[(size_t)gr * 128 + c4];
                        v.x += rv.x; v.y += rv.y; v.z += rv.z; v.w += rv.w;
                    }
                    *(float4*)&of[(size_t)gr * 128 + c4] = v;
                }
            }
        }
        __syncthreads();
    }
}

// ---------------- per-node attention + LN1 (16 lanes per node, 4 nodes per wave) --------
// qkv: [N,384] bf16 (q|k|v). hmid holds skip (f32) on entry; overwritten with LN1 (f32).
// LN1 output additionally written as bf16 over the dead q-columns (own row only).
// MULTI-HEAD: 4 heads x 32 dims; each head = 4 lanes (4 lanes x 8 dims). QK dot reduces
// over xor 1,2 ONLY (per-head). LN reduces over all 16 lanes (factor 1/128).
__global__ __launch_bounds__(256) void attn_kernel(
    u16* __restrict__ qkv,
    const u16* __restrict__ h_in, int ld_h,
    const int* __restrict__ offsets,
    const int* __restrict__ psrc, const float4* __restrict__ pe,
    const float* __restrict__ We_l,
    const float* __restrict__ g1, const float* __restrict__ b1,
    float* __restrict__ hmid, int N)
{
    int tid = threadIdx.x;
    int grp = tid >> 4;                    // 16 nodes per block
    int sub = tid & 15;
    int n = blockIdx.x * 16 + grp;
    if (n >= N) return;
    int d0 = sub * 8;

    float we[4][8];
#pragma unroll
    for (int aa = 0; aa < 4; ++aa) {
        float4 w0 = *(const float4*)&We_l[aa * H + d0];
        float4 w1 = *(const float4*)&We_l[aa * H + d0 + 4];
        we[aa][0] = w0.x; we[aa][1] = w0.y; we[aa][2] = w0.z; we[aa][3] = w0.w;
        we[aa][4] = w1.x; we[aa][5] = w1.y; we[aa][6] = w1.z; we[aa][7] = w1.w;
    }

    ushort8v qraw = *(const ushort8v*)&qkv[(size_t)n * JK + d0];
    float qf[8];
#pragma unroll
    for (int i = 0; i < 8; ++i) qf[i] = bf2f(qraw[i]);

    float m = -INFINITY, ssum = 0.f;
    float a[8] = {0.f, 0.f, 0.f, 0.f, 0.f, 0.f, 0.f, 0.f};
    int e0 = offsets[n], e1 = offsets[n + 1];
    for (int j = e0; j < e1; ++j) {
        int s = psrc[j];
        float4 ea = pe[j];
        const u16* srow = qkv + (size_t)s * JK;
        ushort8v kraw = *(const ushort8v*)&srow[H + d0];
        ushort8v vraw = *(const ushort8v*)&srow[2 * H + d0];
        float part = 0.f, vv[8];
#pragma unroll
        for (int i = 0; i < 8; ++i) {
            float eb = ea.x * we[0][i] + ea.y * we[1][i] + ea.z * we[2][i] + ea.w * we[3][i];
            float kf = bf2f(kraw[i]) + eb;
            vv[i] = bf2f(vraw[i]) + eb;
            part = fmaf(qf[i], kf, part);
        }
        part += __shfl_xor(part, 1);       // per-head reduce over the head's 4 lanes
        part += __shfl_xor(part, 2);       // (NOT 4/8 -- heads are independent!)
        float logit = part * ATT_SCALE;
        float mn = fmaxf(m, logit);
        float corr = __expf(m - mn);       // m=-inf first edge -> corr=0
        float p = __expf(logit - mn);
        ssum = ssum * corr + p;
#pragma unroll
        for (int i = 0; i < 8; ++i) a[i] = a[i] * corr + p * vv[i];
        m = mn;
    }
    float inv = 1.f / (ssum + 1e-16f);

    ushort8v hraw = *(const ushort8v*)&h_in[(size_t)n * ld_h + d0];
    float4 sk0 = *(const float4*)&hmid[(size_t)n * H + d0];
    float4 sk1 = *(const float4*)&hmid[(size_t)n * H + d0 + 4];
    float skf[8] = {sk0.x, sk0.y, sk0.z, sk0.w, sk1.x, sk1.y, sk1.z, sk1.w};
    float tv[8], sum = 0.f, sq = 0.f;
#pragma unroll
    for (int i = 0; i < 8; ++i) {
        tv[i] = bf2f(hraw[i]) + a[i] * inv + skf[i];
        sum += tv[i]; sq += tv[i] * tv[i];
    }
    // LN reduce over the 16-lane group (128 dims, each counted once)
#pragma unroll
    for (int off = 1; off <= 8; off <<= 1) { sum += __shfl_xor(sum, off); sq += __shfl_xor(sq, off); }
    float mean = sum * (1.f / 128.f);
    float var = sq * (1.f / 128.f) - mean * mean;
    float rstd = rsqrtf(var + 1e-5f);
    float4 ga = *(const float4*)&g1[d0];
    float4 gb = *(const float4*)&g1[d0 + 4];
    float4 ba = *(const float4*)&b1[d0];
    float4 bb = *(const float4*)&b1[d0 + 4];
    float gg[8] = {ga.x, ga.y, ga.z, ga.w, gb.x, gb.y, gb.z, gb.w};
    float bbv[8] = {ba.x, ba.y, ba.z, ba.w, bb.x, bb.y, bb.z, bb.w};
    float o[8];
    ushort8v obv;
#pragma unroll
    for (int i = 0; i < 8; ++i) {
        o[i] = (tv[i] - mean) * rstd * gg[i] + bbv[i];
        obv[i] = f2bf(o[i]);
    }
    *(float4*)&hmid[(size_t)n * H + d0]     = make_float4(o[0], o[1], o[2], o[3]);
    *(float4*)&hmid[(size_t)n * H + d0 + 4] = make_float4(o[4], o[5], o[6], o[7]);
    *(ushort8v*)&qkv[(size_t)n * JK + d0] = obv;   // bf16 LN1 over dead q-cols
}

// ---------------- LayerNorm f32 in -> bf16 out (wave per row) ----------------
__global__ __launch_bounds__(256) void ln_kernel(const float* __restrict__ in,
                                                 const float* __restrict__ g,
                                                 const float* __restrict__ b,
                                                 u16* __restrict__ out, int ldo, int N) {
    int wid = threadIdx.x >> 6;
    int lane = threadIdx.x & 63;
    int n = blockIdx.x * 4 + wid;
    if (n >= N) return;
    int d0 = lane * 2;
    float2 t = *(const float2*)&in[(size_t)n * H + d0];
    float sum = t.x + t.y, sq = t.x * t.x + t.y * t.y;
#pragma unroll
    for (int off = 32; off; off >>= 1) { sum += __shfl_xor(sum, off); sq += __shfl_xor(sq, off); }
    float mean = sum * (1.f / 128.f);
    float var = sq * (1.f / 128.f) - mean * mean;
    float rstd = rsqrtf(var + 1e-5f);
    ushort2 s;
    s.x = f2bf((t.x - mean) * rstd * g[d0] + b[d0]);
    s.y = f2bf((t.y - mean) * rstd * g[d0 + 1] + b[d0 + 1]);
    *(ushort2*)&out[(size_t)n * ldo + d0] = s;
}

// ---------------- per-graph softmax pooling (weights cached in LDS) ----------------
#define PCH 512
__global__ __launch_bounds__(256) void pool_kernel(const float* __restrict__ gate,
                                                   const u16* __restrict__ xc,
                                                   const int* __restrict__ gstart,
                                                   const float* __restrict__ u,
                                                   float* __restrict__ pooled, int G) {
    int g = blockIdx.x;
    int t = threadIdx.x;
    int s0 = gstart[g], s1 = gstart[g + 1];
    __shared__ float red[256];
    __shared__ float w[PCH];
    float mx = -INFINITY;
    for (int i = s0 + t; i < s1; i += 256) mx = fmaxf(mx, gate[i]);
    red[t] = mx; __syncthreads();
    for (int off = 128; off; off >>= 1) { if (t < off) red[t] = fmaxf(red[t], red[t + off]); __syncthreads(); }
    float gm = red[0]; __syncthreads();
    float sm = 0.f;
    for (int i = s0 + t; i < s1; i += 256) sm += __expf(gate[i] - gm);
    red[t] = sm; __syncthreads();
    for (int off = 128; off; off >>= 1) { if (t < off) red[t] += red[t + off]; __syncthreads(); }
    float inv = 1.f / (red[0] + 1e-16f);
    float acc0 = 0.f, acc1 = 0.f;
    for (int base = s0; base < s1; base += PCH) {
        int cnt = min(PCH, s1 - base);
        __syncthreads();
        for (int i = t; i < cnt; i += 256) w[i] = __expf(gate[base + i] - gm) * inv;
        __syncthreads();
        for (int c = 0; c < cnt; ++c) {
            const u16* row = xc + (size_t)(base + c) * JK;
            float wc = w[c];
            acc0 = fmaf(wc, bf2f(row[t]), acc0);
            if (t < 128) acc1 = fmaf(wc, bf2f(row[t + 256]), acc1);
        }
    }
    pooled[(size_t)g * (JK + 1) + t] = acc0;
    if (t < 128) pooled[(size_t)g * (JK + 1) + t + 256] = acc1;
    if (t == 0) pooled[(size_t)g * (JK + 1) + JK] = u[g];
}

// ---------------- final MLP head ----------------
__global__ __launch_bounds__(128) void head_kernel(const float* __restrict__ pooled,
                                                   const float* __restrict__ Wh1,
                                                   const float* __restrict__ bh1,
                                                   const float* __restrict__ Wh2,
                                                   const float* __restrict__ bh2,
                                                   float* __restrict__ out, int G) {
    int g = blockIdx.x;
    int j = threadIdx.x;
    __shared__ float hid[128];
    float acc = bh1[j];
    const float* pr = pooled + (size_t)g * (JK + 1);
    for (int k = 0; k < JK + 1; ++k) acc = fmaf(pr[k], Wh1[(size_t)k * H + j], acc);
    hid[j] = fmaxf(acc, 0.f);
    __syncthreads();
    if (j < 3) {
        float o = bh2[j];
        for (int k = 0; k < H; ++k) o += hid[k] * Wh2[k * 3 + j];
        out[(size_t)g * 3 + j] = o;
    }
}

extern "C" void kernel_launch(void* const* d_in, const int* in_sizes, int n_in,
                              void* d_out, int out_size, void* d_ws, size_t ws_size,
                              hipStream_t stream) {
    const float* x     = (const float*)d_in[0];
    const int*   ei    = (const int*)d_in[1];
    const float* eattr = (const float*)d_in[2];
    const int*   batch = (const int*)d_in[3];
    const float* u     = (const float*)d_in[4];
    const float* Win   = (const float*)d_in[5];
    const float* b_in  = (const float*)d_in[6];
    const float* Wq    = (const float*)d_in[7];
    const float* bq    = (const float*)d_in[8];
    const float* Wk    = (const float*)d_in[9];
    const float* bk    = (const float*)d_in[10];
    const float* Wv    = (const float*)d_in[11];
    const float* bv    = (const float*)d_in[12];
    const float* We    = (const float*)d_in[13];
    const float* Wskip = (const float*)d_in[14];
    const float* bskip = (const float*)d_in[15];
    const float* ln1_g = (const float*)d_in[16];
    const float* ln1_b = (const float*)d_in[17];
    const float* Wf1   = (const float*)d_in[18];
    const float* bf1   = (const float*)d_in[19];
    const float* Wf2   = (const float*)d_in[20];
    const float* bf2   = (const float*)d_in[21];
    const float* ln2_g = (const float*)d_in[22];
    const float* ln2_b = (const float*)d_in[23];
    const float* Wg1   = (const float*)d_in[24];
    const float* bg1   = (const float*)d_in[25];
    const float* Wg2   = (const float*)d_in[26];
    const float* bg2   = (const float*)d_in[27];
    const float* Wh1   = (const float*)d_in[28];
    const float* bh1   = (const float*)d_in[29];
    const float* Wh2   = (const float*)d_in[30];
    const float* bh2   = (const float*)d_in[31];

    const int N = in_sizes[3];
    const int E = in_sizes[1] / 2;
    const int G = in_sizes[4];

    // workspace carve-up (256B aligned) — total ~215 MB
    char* p = (char*)d_ws;
    auto alloc = [&](size_t bytes) { char* r = p; p += (bytes + 255) & ~(size_t)255; return r; };
    int*    counts  = (int*)alloc((size_t)N * 4);
    int*    cursor  = (int*)alloc((size_t)N * 4);
    int*    offsets = (int*)alloc((size_t)(N + 1) * 4);
    int*    psrc    = (int*)alloc((size_t)E * 4);
    float4* pe      = (float4*)alloc((size_t)E * 16);
    int*    gstart  = (int*)alloc((size_t)(G + 1) * 4);
    int*    bsum    = (int*)alloc(128 * 4);
    int*    boffs   = (int*)alloc(128 * 4);
    float*  gate    = (float*)alloc((size_t)N * 4);
    float*  pooled  = (float*)alloc((size_t)G * (JK + 1) * 4);
    u16*    WT      = (u16*)alloc((size_t)442368 * 2);            // all weights bf16, transposed [Ncol][K]
    float*  hmid    = (float*)alloc((size_t)N * H * 4);           // f32 [N,128]
    u16*    xc      = (u16*)alloc((size_t)N * JK * 2);            // bf16 [N,384]
    u16*    qkv     = (u16*)alloc((size_t)N * JK * 2);            // bf16 [N,384]; heavily reused

    // WT layout offsets (elems)
    const int QKVS_OFF = 0;            // per layer: 512x128 (q|k|v|skip rows)
    const int F1_OFF   = 3 * 65536;    // per layer: 256x128
    const int F2_OFF   = F1_OFF + 3 * 32768;  // per layer: 128x256
    const int G1_OFF   = F2_OFF + 3 * 32768;  // 128x384

    hipMemsetAsync(counts, 0, (size_t)N * 4, stream);
    hipMemsetAsync(cursor, 0, (size_t)N * 4, stream);

    int eb = cdiv(E, 256);
    int nb = cdiv(N, 1024);
    hist_kernel<<<eb, 256, 0, stream>>>(ei, counts, E);
    scan1_kernel<<<nb, 256, 0, stream>>>(counts, offsets, bsum, N);
    scan2_kernel<<<1, 128, 0, stream>>>(bsum, boffs, offsets, nb, N);
    scan3_kernel<<<nb, 256, 0, stream>>>(offsets, boffs, N);
    scatter_kernel<<<eb, 256, 0, stream>>>(ei, eattr, offsets, cursor, psrc, pe, E);
    graph_bounds_kernel<<<cdiv(G + 1, 256), 256, 0, stream>>>(batch, gstart, N, G);

    // weight conversion (19 matrices)
    TA ta;
    for (int l = 0; l < 3; ++l) {
        ta.d[l * 4 + 0] = { Wq    + (size_t)l * 16384, QKVS_OFF + l * 65536 + 0,     128, 128 };
        ta.d[l * 4 + 1] = { Wk    + (size_t)l * 16384, QKVS_OFF + l * 65536 + 16384, 128, 128 };
        ta.d[l * 4 + 2] = { Wv    + (size_t)l * 16384, QKVS_OFF + l * 65536 + 32768, 128, 128 };
        ta.d[l * 4 + 3] = { Wskip + (size_t)l * 16384, QKVS_OFF + l * 65536 + 49152, 128, 128 };
        ta.d[12 + l]    = { Wf1   + (size_t)l * 32768, F1_OFF   + l * 32768,         128, 256 };
        ta.d[15 + l]    = { Wf2   + (size_t)l * 32768, F2_OFF   + l * 32768,         256, 128 };
    }
    ta.d[18] = { Wg1, G1_OFF, 384, 128 };
    dim3 wg(cdiv(49152, 256), 19);
    wconv_kernel<<<wg, 256, 0, stream>>>(ta, WT);

    input_proj_kernel<<<cdiv(N * 64, 256), 256, 0, stream>>>(x, Win, b_in, xc, JK, N);

    int gb = cdiv(N, 128);
    int nb16 = cdiv(N, 16);
    int nb4 = cdiv(N, 4);
    for (int l = 0; l < LAYERS; ++l) {
        const u16* hin = xc + (size_t)((l == 0) ? 0 : (l - 1) * H);
        // fused q|k|v|skip: q,k,v -> bf16 qkv; skip -> f32 hmid
        gemm_mfma<0, 4><<<gb * 4, 256, 0, stream>>>(
            hin, JK, WT + QKVS_OFF + (size_t)l * 65536, 128,
            bq + l * H, bk + l * H, bv + l * H, bskip + l * H,
            nullptr, qkv, hmid, N);
        attn_kernel<<<nb16, 256, 0, stream>>>(qkv, hin, JK, offsets, psrc, pe,
                                              We + (size_t)l * 4 * H, ln1_g + l * H, ln1_b + l * H,
                                              hmid, N);
        // FF1: A = ln1 bf16 (qkv cols 0..127) -> relu out bf16 at qkv cols 128..383
        gemm_mfma<1, 2><<<gb * 2, 256, 0, stream>>>(
            qkv, JK, WT + F1_OFF + (size_t)l * 32768, 128,
            bf1 + (size_t)l * FFDIM, nullptr, nullptr, nullptr,
            nullptr, qkv + H, nullptr, N);
        // FF2: A = ff1 bf16 (qkv cols 128..383), resid = hmid f32, out hmid f32
        gemm_mfma<2, 1><<<gb, 256, 0, stream>>>(
            qkv + H, JK, WT + F2_OFF + (size_t)l * 32768, 256,
            bf2 + (size_t)l * H, nullptr, nullptr, nullptr,
            hmid, nullptr, hmid, N);
        ln_kernel<<<nb4, 256, 0, stream>>>(hmid, ln2_g + l * H, ln2_b + l * H,
                                           xc + (size_t)l * H, JK, N);
    }

    // gate: A = xc bf16 K=384, fused relu+dot(Wg2)+bg2 -> gate[n]
    gemm_mfma<3, 1><<<gb, 256, 0, stream>>>(
        xc, JK, WT + G1_OFF, JK,
        bg1, Wg2, bg2, nullptr,
        nullptr, nullptr, gate, N);
    pool_kernel<<<G, 256, 0, stream>>>(gate, xc, gstart, u, pooled, G);
    head_kernel<<<G, 128, 0, stream>>>(pooled, Wh1, bh1, Wh2, bh2, (float*)d_out, G);
}

// Round 8
// 702.142 us; speedup vs baseline: 3.0328x; 1.0323x over previous
//
#include <hip/hip_runtime.h>
#include <math.h>

#define H 128
#define LAYERS 3
#define FFDIM 256
#define JK 384
#define ATT_SCALE 0.17677669529663687f

typedef unsigned short u16;
typedef __attribute__((ext_vector_type(4))) float f32x4;
typedef __attribute__((ext_vector_type(8))) short short8;
typedef __attribute__((ext_vector_type(8))) unsigned short ushort8v;

static inline int cdiv(int a, int b) { return (a + b - 1) / b; }

static __device__ __forceinline__ float bf2f(u16 u) {
    union { unsigned int i; float f; } v; v.i = ((unsigned int)u) << 16; return v.f;
}
static __device__ __forceinline__ u16 f2bf(float f) {
    union { float f; unsigned int i; } v; v.f = f;
    unsigned int r = v.i + 0x7FFFu + ((v.i >> 16) & 1u);
    return (u16)(r >> 16);
}

// ---------------- CSR build over dst ----------------
__global__ void hist_kernel(const int* __restrict__ ei, int* __restrict__ counts, int E) {
    int e = blockIdx.x * blockDim.x + threadIdx.x;
    if (e >= E) return;
    atomicAdd(&counts[ei[E + e]], 1);
}

// 3-phase scan: block-local scan -> block-sum scan -> add back
__global__ __launch_bounds__(256) void scan1_kernel(const int* __restrict__ counts,
                                                    int* __restrict__ offsets,
                                                    int* __restrict__ bsum, int N) {
    __shared__ int sh[256];
    int t = threadIdx.x;
    int base = blockIdx.x * 1024 + t * 4;
    int v0 = 0, v1 = 0, v2 = 0, v3 = 0;
    if (base + 3 < N) {
        int4 q = *(const int4*)&counts[base];
        v0 = q.x; v1 = q.y; v2 = q.z; v3 = q.w;
    } else {
        if (base < N) v0 = counts[base];
        if (base + 1 < N) v1 = counts[base + 1];
        if (base + 2 < N) v2 = counts[base + 2];
        if (base + 3 < N) v3 = counts[base + 3];
    }
    int ts = v0 + v1 + v2 + v3;
    sh[t] = ts; __syncthreads();
    for (int off = 1; off < 256; off <<= 1) {
        int x = (t >= off) ? sh[t - off] : 0;
        __syncthreads(); sh[t] += x; __syncthreads();
    }
    int excl = sh[t] - ts;
    if (base < N)     offsets[base]     = excl;
    if (base + 1 < N) offsets[base + 1] = excl + v0;
    if (base + 2 < N) offsets[base + 2] = excl + v0 + v1;
    if (base + 3 < N) offsets[base + 3] = excl + v0 + v1 + v2;
    if (t == 255) bsum[blockIdx.x] = sh[255];
}

__global__ __launch_bounds__(128) void scan2_kernel(const int* __restrict__ bsum,
                                                    int* __restrict__ boffs,
                                                    int* __restrict__ offsets, int nb, int N) {
    __shared__ int sh[128];
    int t = threadIdx.x;
    int s = (t < nb) ? bsum[t] : 0;
    sh[t] = s; __syncthreads();
    for (int off = 1; off < 128; off <<= 1) {
        int x = (t >= off) ? sh[t - off] : 0;
        __syncthreads(); sh[t] += x; __syncthreads();
    }
    if (t < nb) boffs[t] = sh[t] - s;
    if (t == 0) offsets[N] = sh[nb - 1];
}

__global__ __launch_bounds__(256) void scan3_kernel(int* __restrict__ offsets,
                                                    const int* __restrict__ boffs, int N) {
    int add = boffs[blockIdx.x];
    int base = blockIdx.x * 1024 + threadIdx.x * 4;
#pragma unroll
    for (int i = 0; i < 4; ++i)
        if (base + i < N) offsets[base + i] += add;
}

// scatter with payload: psrc = src node id, pe = edge_attr copy (permuted order)
__global__ void scatter_kernel(const int* __restrict__ ei, const float* __restrict__ eattr,
                               const int* __restrict__ offsets,
                               int* __restrict__ cursor, int* __restrict__ psrc,
                               float4* __restrict__ pe, int E) {
    int e = blockIdx.x * blockDim.x + threadIdx.x;
    if (e >= E) return;
    int d = ei[E + e];
    int pos = atomicAdd(&cursor[d], 1);
    int o = offsets[d] + pos;
    psrc[o] = ei[e];
    pe[o] = *(const float4*)&eattr[(size_t)e * 4];
}

__global__ void graph_bounds_kernel(const int* __restrict__ batch, int* __restrict__ gstart,
                                    int N, int G) {
    int g = blockIdx.x * blockDim.x + threadIdx.x;
    if (g > G) return;
    int lo = 0, hi = N;
    while (lo < hi) { int mid = (lo + hi) >> 1; if (batch[mid] < g) lo = mid + 1; else hi = mid; }
    gstart[g] = lo;
}

// ---------------- weight transpose+convert: WT[c*K+k] = bf16(W[k*N+c]) ----------------
struct TD { const float* src; int dstoff, K, N; };
struct TA { TD d[19]; };

__global__ __launch_bounds__(256) void wconv_kernel(TA a, u16* __restrict__ WT) {
    TD d = a.d[blockIdx.y];
    int i = blockIdx.x * 256 + threadIdx.x;
    int tot = d.K * d.N;
    if (i >= tot) return;
    int c = i / d.K, k = i - c * d.K;
    WT[d.dstoff + i] = f2bf(d.src[(size_t)k * d.N + c]);
}

// ---------------- input projection h0 = x @ Win + b -> bf16, strided into xc cols 0..127
__global__ __launch_bounds__(256) void input_proj_kernel(const float* __restrict__ x,
                                                         const float* __restrict__ Win,
                                                         const float* __restrict__ b_in,
                                                         u16* __restrict__ h, int ldh, int N) {
    int idx = blockIdx.x * 256 + threadIdx.x;     // N*64 threads, 2 cols each
    int n = idx >> 6, c = (idx & 63) * 2;
    if (n >= N) return;
    float4 xv = *(const float4*)&x[(size_t)n * 4];
    float o0 = b_in[c]     + xv.x * Win[c]     + xv.y * Win[H + c]     + xv.z * Win[2 * H + c]     + xv.w * Win[3 * H + c];
    float o1 = b_in[c + 1] + xv.x * Win[c + 1] + xv.y * Win[H + c + 1] + xv.z * Win[2 * H + c + 1] + xv.w * Win[3 * H + c + 1];
    ushort2 s; s.x = f2bf(o0); s.y = f2bf(o1);
    *(ushort2*)&h[(size_t)n * ldh + c] = s;
}

// ---------------- MFMA bf16 GEMM ----------------
// C[M,128] = A[M,K](bf16) @ WT[128,K]^T(bf16), XOR-swizzled LDS tiles, 4 waves x (64x64).
// 1D grid = gb*NBY, bijective XCD swizzle, by fastest. LDS-staged coalesced epilogue.
// MODE 0: qkv+skip (NBY=4; by<3 -> bf16 obf+by*128 ld384; by==3 -> bf16 obf2 ld128 [skip])
// MODE 1: ff1      (NBY=2; bias b0+by*128; relu; bf16 obf+by*128 ld384)
// MODE 2: ff2      (resid16 bf16 ld384 += at copy-out; f32 of32 ld128)
// MODE 3: gate1    (fused: relu + dot(Wg2=b1) + bg2(=b2) -> of32 = gate[n])
__device__ __forceinline__ void stage_tile(const u16* __restrict__ g, int ld, int row0,
                                           int nrows, int kt, u16* __restrict__ sm, int t) {
#pragma unroll
    for (int i = 0; i < 4; ++i) {
        int f = i * 256 + t;              // chunk id 0..1023
        int row = f >> 3, ck = f & 7;
        int n = row0 + row; if (n >= nrows) n = nrows - 1;
        uint4 v = *(const uint4*)(g + (size_t)n * ld + kt + ck * 8);
        int sw = ck ^ (row & 7);
        *(uint4*)(sm + row * 64 + sw * 8) = v;
    }
}

template <int MODE, int NBY>
__global__ __launch_bounds__(256) void gemm_mfma(
    const u16* __restrict__ A, int lda,
    const u16* __restrict__ WT, int K,
    const float* __restrict__ b0, const float* __restrict__ b1,
    const float* __restrict__ b2, const float* __restrict__ b3,
    const u16* __restrict__ resid16,
    u16* __restrict__ obf, u16* __restrict__ obf2, float* __restrict__ of32,
    int nrows)
{
    alignas(16) __shared__ char smemraw[33792];   // A/B tiles (32KB) then reused as f32 stage[64][132]
    u16* Asm = (u16*)smemraw;
    u16* Bsm = (u16*)(smemraw + 16384);
    float* stage = (float*)smemraw;
    int t = threadIdx.x;
    int lane = t & 63, wid = t >> 6;
    int wr = wid >> 1, wc = wid & 1;

    // bijective XCD swizzle: contiguous swz chunk per XCD; by fastest within swz
    int T = gridDim.x, id = blockIdx.x;
    int qd = T >> 3, rr = T & 7;
    int xcd = id & 7, pos = id >> 3;
    int swz = (xcd < rr ? xcd * (qd + 1) : rr * (qd + 1) + (xcd - rr) * qd) + pos;
    int by = swz & (NBY - 1);
    int row0 = (swz / NBY) * 128;

    const u16* WTb = WT + (size_t)by * 128 * K;

    f32x4 acc[4][4] = {};

    for (int kt = 0; kt < K; kt += 64) {
        stage_tile(A, lda, row0, nrows, kt, Asm, t);
        stage_tile(WTb, K, 0, 128, kt, Bsm, t);
        __syncthreads();
        int g = lane >> 4;
        int l15 = lane & 15;
#pragma unroll
        for (int kk = 0; kk < 2; ++kk) {
            int cb = kk * 4 + g;
            short8 af[4], bf[4];
#pragma unroll
            for (int mi = 0; mi < 4; ++mi) {
                int r = wr * 64 + mi * 16 + l15;
                af[mi] = *(const short8*)(Asm + r * 64 + ((cb ^ (r & 7)) * 8));
            }
#pragma unroll
            for (int nj = 0; nj < 4; ++nj) {
                int c = wc * 64 + nj * 16 + l15;
                bf[nj] = *(const short8*)(Bsm + c * 64 + ((cb ^ (c & 7)) * 8));
            }
#pragma unroll
            for (int mi = 0; mi < 4; ++mi)
#pragma unroll
                for (int nj = 0; nj < 4; ++nj)
                    acc[mi][nj] = __builtin_amdgcn_mfma_f32_16x16x32_bf16(af[mi], bf[nj], acc[mi][nj], 0, 0, 0);
        }
        __syncthreads();
    }

    int g = lane >> 4, l15 = lane & 15;

    if (MODE == 3) {
        // fused gate: gate[n] = relu(acc+bg1) . Wg2 + bg2
        float* gsum = (float*)Asm;          // reuse LDS (post-barrier)
        float part[4][4];
#pragma unroll
        for (int mi = 0; mi < 4; ++mi)
#pragma unroll
            for (int r = 0; r < 4; ++r) part[mi][r] = 0.f;
#pragma unroll
        for (int nj = 0; nj < 4; ++nj) {
            int col = wc * 64 + nj * 16 + l15;
            float bb = b0[col];
            float w2 = b1[col];
#pragma unroll
            for (int mi = 0; mi < 4; ++mi)
#pragma unroll
                for (int r = 0; r < 4; ++r) {
                    float v = fmaxf(acc[mi][nj][r] + bb, 0.f);
                    part[mi][r] = fmaf(v, w2, part[mi][r]);
                }
        }
#pragma unroll
        for (int off = 1; off <= 8; off <<= 1)
#pragma unroll
            for (int mi = 0; mi < 4; ++mi)
#pragma unroll
                for (int r = 0; r < 4; ++r) part[mi][r] += __shfl_xor(part[mi][r], off);
        if (wc == 0 && l15 == 0) {
#pragma unroll
            for (int mi = 0; mi < 4; ++mi)
#pragma unroll
                for (int r = 0; r < 4; ++r)
                    gsum[wr * 64 + mi * 16 + g * 4 + r] = part[mi][r];
        }
        __syncthreads();
        if (wc == 1 && l15 == 0) {
            float bg2v = b2[0];
#pragma unroll
            for (int mi = 0; mi < 4; ++mi)
#pragma unroll
                for (int r = 0; r < 4; ++r) {
                    int lr = wr * 64 + mi * 16 + g * 4 + r;
                    int n = row0 + lr;
                    if (n < nrows) of32[n] = part[mi][r] + gsum[lr] + bg2v;
                }
        }
        return;
    }

    const float* bias;
    u16* ob = nullptr; int ldob = 384; float* of = nullptr;
    if (MODE == 0) {
        bias = (by == 0) ? b0 : (by == 1) ? b1 : (by == 2) ? b2 : b3;
        if (by < 3) ob = obf + by * 128;
        else { ob = obf2; ldob = 128; }
    } else if (MODE == 1) {
        bias = b0 + by * 128;
        ob = obf + by * 128;
    } else {
        bias = b0;
        of = of32;
    }

    // staged epilogue: 2 phases x 64 rows via LDS, fully coalesced global writes
#pragma unroll
    for (int p = 0; p < 2; ++p) {
        if (wr == p) {
#pragma unroll
            for (int nj = 0; nj < 4; ++nj) {
                int col = wc * 64 + nj * 16 + l15;
                float bb = bias[col];
#pragma unroll
                for (int mi = 0; mi < 4; ++mi)
#pragma unroll
                    for (int r = 0; r < 4; ++r) {
                        float v = acc[mi][nj][r] + bb;
                        if (MODE == 1) v = fmaxf(v, 0.f);
                        stage[(mi * 16 + g * 4 + r) * 132 + col] = v;
                    }
            }
        }
        __syncthreads();
        if (ob) {
            // bf16 out: 16 lanes x ushort8 = 256B contiguous per row segment
#pragma unroll
            for (int it = 0; it < 4; ++it) {
                int lr = it * 16 + (t >> 4);
                int gr = row0 + p * 64 + lr;
                if (gr < nrows) {
                    int c8 = l15 * 8;
                    ushort8v o;
#pragma unroll
                    for (int i = 0; i < 8; ++i) o[i] = f2bf(stage[lr * 132 + c8 + i]);
                    *(ushort8v*)&ob[(size_t)gr * ldob + c8] = o;
                }
            }
        } else {
            // f32 out, ld 128: 32 lanes x float4 = 512B contiguous per row
            int l31 = t & 31;
#pragma unroll
            for (int it = 0; it < 8; ++it) {
                int lr = it * 8 + (t >> 5);
                int gr = row0 + p * 64 + lr;
                if (gr < nrows) {
                    int c4 = l31 * 4;
                    float4 v = *(float4*)&stage[lr * 132 + c4];
                    if (MODE == 2) {
                        ushort4 rv = *(const ushort4*)&resid16[(size_t)gr * 384 + c4];
                        v.x += bf2f(rv.x); v.y += bf2f(rv.y); v.z += bf2f(rv.z); v.w += bf2f(rv.w);
                    }
                    *(float4*)&of[(size_t)gr * 128 + c4] = v;
                }
            }
        }
        __syncthreads();
    }
}

// ---------------- per-node attention + LN1 (16 lanes per node, 4 nodes per wave) --------
// qkv: [N,384] bf16 (q|k|v). skipb: [N,128] bf16 skip. LN1 out written as bf16 over the
// dead q-columns only (no f32 hmid traffic).
// MULTI-HEAD: 4 heads x 32 dims; head = sub>>2 (4 lanes x 8 dims). QK dot reduces over
// xor 1,2 ONLY. Edge-bias fused algebraically:
//   q.(k+e) = q.k + ea . qe        (qe[a] = per-head q . We[a], precomputed)
//   sum_j p_j (v+e_j) = sum p_j v  +  wsum @ We   (wsum[a] = sum_j p_j ea_j[a])
__global__ __launch_bounds__(256) void attn_kernel(
    u16* __restrict__ qkv,
    const u16* __restrict__ h_in, int ld_h,
    const u16* __restrict__ skipb,
    const int* __restrict__ offsets,
    const int* __restrict__ psrc, const float4* __restrict__ pe,
    const float* __restrict__ We_l,
    const float* __restrict__ g1, const float* __restrict__ b1,
    int N)
{
    int tid = threadIdx.x;
    int grp = tid >> 4;                    // 16 nodes per block
    int sub = tid & 15;
    int n = blockIdx.x * 16 + grp;
    if (n >= N) return;
    int d0 = sub * 8;

    float we[4][8];
#pragma unroll
    for (int aa = 0; aa < 4; ++aa) {
        float4 w0 = *(const float4*)&We_l[aa * H + d0];
        float4 w1 = *(const float4*)&We_l[aa * H + d0 + 4];
        we[aa][0] = w0.x; we[aa][1] = w0.y; we[aa][2] = w0.z; we[aa][3] = w0.w;
        we[aa][4] = w1.x; we[aa][5] = w1.y; we[aa][6] = w1.z; we[aa][7] = w1.w;
    }

    ushort8v qraw = *(const ushort8v*)&qkv[(size_t)n * JK + d0];
    float qf[8];
#pragma unroll
    for (int i = 0; i < 8; ++i) qf[i] = bf2f(qraw[i]);

    // qe[a] = per-head dot(q, We[a]) -- uniform within each head quad after reduce
    float qe[4];
#pragma unroll
    for (int aa = 0; aa < 4; ++aa) {
        float s = 0.f;
#pragma unroll
        for (int i = 0; i < 8; ++i) s = fmaf(qf[i], we[aa][i], s);
        s += __shfl_xor(s, 1);
        s += __shfl_xor(s, 2);
        qe[aa] = s;
    }

    float m = -INFINITY, ssum = 0.f;
    float a[8] = {0.f, 0.f, 0.f, 0.f, 0.f, 0.f, 0.f, 0.f};
    float ws0 = 0.f, ws1 = 0.f, ws2 = 0.f, ws3 = 0.f;
    int e0 = offsets[n], e1 = offsets[n + 1];
    for (int j = e0; j < e1; ++j) {
        int s = psrc[j];
        float4 ea = pe[j];
        const u16* srow = qkv + (size_t)s * JK;
        ushort8v kraw = *(const ushort8v*)&srow[H + d0];
        ushort8v vraw = *(const ushort8v*)&srow[2 * H + d0];
        float part = 0.f;
#pragma unroll
        for (int i = 0; i < 8; ++i) part = fmaf(qf[i], bf2f(kraw[i]), part);
        part += __shfl_xor(part, 1);       // per-head reduce over the head's 4 lanes
        part += __shfl_xor(part, 2);
        float logit = (part + ea.x * qe[0] + ea.y * qe[1] + ea.z * qe[2] + ea.w * qe[3]) * ATT_SCALE;
        float mn = fmaxf(m, logit);
        float corr = __expf(m - mn);       // m=-inf first edge -> corr=0
        float p = __expf(logit - mn);
        ssum = ssum * corr + p;
#pragma unroll
        for (int i = 0; i < 8; ++i) a[i] = a[i] * corr + p * bf2f(vraw[i]);
        ws0 = ws0 * corr + p * ea.x;
        ws1 = ws1 * corr + p * ea.y;
        ws2 = ws2 * corr + p * ea.z;
        ws3 = ws3 * corr + p * ea.w;
        m = mn;
    }
    float inv = 1.f / (ssum + 1e-16f);
    // fold the e-bias back into the v aggregate: a += wsum @ We
#pragma unroll
    for (int i = 0; i < 8; ++i)
        a[i] += ws0 * we[0][i] + ws1 * we[1][i] + ws2 * we[2][i] + ws3 * we[3][i];

    ushort8v hraw = *(const ushort8v*)&h_in[(size_t)n * ld_h + d0];
    ushort8v skraw = *(const ushort8v*)&skipb[(size_t)n * H + d0];
    float tv[8], sum = 0.f, sq = 0.f;
#pragma unroll
    for (int i = 0; i < 8; ++i) {
        tv[i] = bf2f(hraw[i]) + a[i] * inv + bf2f(skraw[i]);
        sum += tv[i]; sq += tv[i] * tv[i];
    }
    // LN reduce over the 16-lane group (128 dims, each counted once)
#pragma unroll
    for (int off = 1; off <= 8; off <<= 1) { sum += __shfl_xor(sum, off); sq += __shfl_xor(sq, off); }
    float mean = sum * (1.f / 128.f);
    float var = sq * (1.f / 128.f) - mean * mean;
    float rstd = rsqrtf(var + 1e-5f);
    float4 ga = *(const float4*)&g1[d0];
    float4 gb = *(const float4*)&g1[d0 + 4];
    float4 ba = *(const float4*)&b1[d0];
    float4 bb = *(const float4*)&b1[d0 + 4];
    float gg[8] = {ga.x, ga.y, ga.z, ga.w, gb.x, gb.y, gb.z, gb.w};
    float bbv[8] = {ba.x, ba.y, ba.z, ba.w, bb.x, bb.y, bb.z, bb.w};
    ushort8v obv;
#pragma unroll
    for (int i = 0; i < 8; ++i)
        obv[i] = f2bf((tv[i] - mean) * rstd * gg[i] + bbv[i]);
    *(ushort8v*)&qkv[(size_t)n * JK + d0] = obv;   // bf16 LN1 over dead q-cols
}

// ---------------- LayerNorm f32 in -> bf16 out (wave per row) ----------------
__global__ __launch_bounds__(256) void ln_kernel(const float* __restrict__ in,
                                                 const float* __restrict__ g,
                                                 const float* __restrict__ b,
                                                 u16* __restrict__ out, int ldo, int N) {
    int wid = threadIdx.x >> 6;
    int lane = threadIdx.x & 63;
    int n = blockIdx.x * 4 + wid;
    if (n >= N) return;
    int d0 = lane * 2;
    float2 t = *(const float2*)&in[(size_t)n * H + d0];
    float sum = t.x + t.y, sq = t.x * t.x + t.y * t.y;
#pragma unroll
    for (int off = 32; off; off >>= 1) { sum += __shfl_xor(sum, off); sq += __shfl_xor(sq, off); }
    float mean = sum * (1.f / 128.f);
    float var = sq * (1.f / 128.f) - mean * mean;
    float rstd = rsqrtf(var + 1e-5f);
    ushort2 s;
    s.x = f2bf((t.x - mean) * rstd * g[d0] + b[d0]);
    s.y = f2bf((t.y - mean) * rstd * g[d0 + 1] + b[d0 + 1]);
    *(ushort2*)&out[(size_t)n * ldo + d0] = s;
}

// ---------------- per-graph softmax pooling (weights cached in LDS) ----------------
#define PCH 512
__global__ __launch_bounds__(256) void pool_kernel(const float* __restrict__ gate,
                                                   const u16* __restrict__ xc,
                                                   const int* __restrict__ gstart,
                                                   const float* __restrict__ u,
                                                   float* __restrict__ pooled, int G) {
    int g = blockIdx.x;
    int t = threadIdx.x;
    int s0 = gstart[g], s1 = gstart[g + 1];
    __shared__ float red[256];
    __shared__ float w[PCH];
    float mx = -INFINITY;
    for (int i = s0 + t; i < s1; i += 256) mx = fmaxf(mx, gate[i]);
    red[t] = mx; __syncthreads();
    for (int off = 128; off; off >>= 1) { if (t < off) red[t] = fmaxf(red[t], red[t + off]); __syncthreads(); }
    float gm = red[0]; __syncthreads();
    float sm = 0.f;
    for (int i = s0 + t; i < s1; i += 256) sm += __expf(gate[i] - gm);
    red[t] = sm; __syncthreads();
    for (int off = 128; off; off >>= 1) { if (t < off) red[t] += red[t + off]; __syncthreads(); }
    float inv = 1.f / (red[0] + 1e-16f);
    float acc0 = 0.f, acc1 = 0.f;
    for (int base = s0; base < s1; base += PCH) {
        int cnt = min(PCH, s1 - base);
        __syncthreads();
        for (int i = t; i < cnt; i += 256) w[i] = __expf(gate[base + i] - gm) * inv;
        __syncthreads();
        for (int c = 0; c < cnt; ++c) {
            const u16* row = xc + (size_t)(base + c) * JK;
            float wc = w[c];
            acc0 = fmaf(wc, bf2f(row[t]), acc0);
            if (t < 128) acc1 = fmaf(wc, bf2f(row[t + 256]), acc1);
        }
    }
    pooled[(size_t)g * (JK + 1) + t] = acc0;
    if (t < 128) pooled[(size_t)g * (JK + 1) + t + 256] = acc1;
    if (t == 0) pooled[(size_t)g * (JK + 1) + JK] = u[g];
}

// ---------------- final MLP head ----------------
__global__ __launch_bounds__(128) void head_kernel(const float* __restrict__ pooled,
                                                   const float* __restrict__ Wh1,
                                                   const float* __restrict__ bh1,
                                                   const float* __restrict__ Wh2,
                                                   const float* __restrict__ bh2,
                                                   float* __restrict__ out, int G) {
    int g = blockIdx.x;
    int j = threadIdx.x;
    __shared__ float hid[128];
    float acc = bh1[j];
    const float* pr = pooled + (size_t)g * (JK + 1);
    for (int k = 0; k < JK + 1; ++k) acc = fmaf(pr[k], Wh1[(size_t)k * H + j], acc);
    hid[j] = fmaxf(acc, 0.f);
    __syncthreads();
    if (j < 3) {
        float o = bh2[j];
        for (int k = 0; k < H; ++k) o += hid[k] * Wh2[k * 3 + j];
        out[(size_t)g * 3 + j] = o;
    }
}

extern "C" void kernel_launch(void* const* d_in, const int* in_sizes, int n_in,
                              void* d_out, int out_size, void* d_ws, size_t ws_size,
                              hipStream_t stream) {
    const float* x     = (const float*)d_in[0];
    const int*   ei    = (const int*)d_in[1];
    const float* eattr = (const float*)d_in[2];
    const int*   batch = (const int*)d_in[3];
    const float* u     = (const float*)d_in[4];
    const float* Win   = (const float*)d_in[5];
    const float* b_in  = (const float*)d_in[6];
    const float* Wq    = (const float*)d_in[7];
    const float* bq    = (const float*)d_in[8];
    const float* Wk    = (const float*)d_in[9];
    const float* bk    = (const float*)d_in[10];
    const float* Wv    = (const float*)d_in[11];
    const float* bv    = (const float*)d_in[12];
    const float* We    = (const float*)d_in[13];
    const float* Wskip = (const float*)d_in[14];
    const float* bskip = (const float*)d_in[15];
    const float* ln1_g = (const float*)d_in[16];
    const float* ln1_b = (const float*)d_in[17];
    const float* Wf1   = (const float*)d_in[18];
    const float* bf1   = (const float*)d_in[19];
    const float* Wf2   = (const float*)d_in[20];
    const float* bf2   = (const float*)d_in[21];
    const float* ln2_g = (const float*)d_in[22];
    const float* ln2_b = (const float*)d_in[23];
    const float* Wg1   = (const float*)d_in[24];
    const float* bg1   = (const float*)d_in[25];
    const float* Wg2   = (const float*)d_in[26];
    const float* bg2   = (const float*)d_in[27];
    const float* Wh1   = (const float*)d_in[28];
    const float* bh1   = (const float*)d_in[29];
    const float* Wh2   = (const float*)d_in[30];
    const float* bh2   = (const float*)d_in[31];

    const int N = in_sizes[3];
    const int E = in_sizes[1] / 2;
    const int G = in_sizes[4];

    // workspace carve-up (256B aligned) — total ~215 MB
    char* p = (char*)d_ws;
    auto alloc = [&](size_t bytes) { char* r = p; p += (bytes + 255) & ~(size_t)255; return r; };
    int*    counts  = (int*)alloc((size_t)N * 4);
    int*    cursor  = (int*)alloc((size_t)N * 4);
    int*    offsets = (int*)alloc((size_t)(N + 1) * 4);
    int*    psrc    = (int*)alloc((size_t)E * 4);
    float4* pe      = (float4*)alloc((size_t)E * 16);
    int*    gstart  = (int*)alloc((size_t)(G + 1) * 4);
    int*    bsum    = (int*)alloc(128 * 4);
    int*    boffs   = (int*)alloc(128 * 4);
    float*  gate    = (float*)alloc((size_t)N * 4);
    float*  pooled  = (float*)alloc((size_t)G * (JK + 1) * 4);
    u16*    WT      = (u16*)alloc((size_t)442368 * 2);            // all weights bf16, transposed [Ncol][K]
    float*  hmid    = (float*)alloc((size_t)N * H * 4);           // f32 [N,128] (FF2 out / LN2 in)
    u16*    skipb   = (u16*)hmid;                                 // bf16 [N,128] skip (dead before FF2 writes)
    u16*    xc      = (u16*)alloc((size_t)N * JK * 2);            // bf16 [N,384]
    u16*    qkv     = (u16*)alloc((size_t)N * JK * 2);            // bf16 [N,384]; heavily reused

    // WT layout offsets (elems)
    const int QKVS_OFF = 0;            // per layer: 512x128 (q|k|v|skip rows)
    const int F1_OFF   = 3 * 65536;    // per layer: 256x128
    const int F2_OFF   = F1_OFF + 3 * 32768;  // per layer: 128x256
    const int G1_OFF   = F2_OFF + 3 * 32768;  // 128x384

    hipMemsetAsync(counts, 0, (size_t)N * 4, stream);
    hipMemsetAsync(cursor, 0, (size_t)N * 4, stream);

    int eb = cdiv(E, 256);
    int nb = cdiv(N, 1024);
    hist_kernel<<<eb, 256, 0, stream>>>(ei, counts, E);
    scan1_kernel<<<nb, 256, 0, stream>>>(counts, offsets, bsum, N);
    scan2_kernel<<<1, 128, 0, stream>>>(bsum, boffs, offsets, nb, N);
    scan3_kernel<<<nb, 256, 0, stream>>>(offsets, boffs, N);
    scatter_kernel<<<eb, 256, 0, stream>>>(ei, eattr, offsets, cursor, psrc, pe, E);
    graph_bounds_kernel<<<cdiv(G + 1, 256), 256, 0, stream>>>(batch, gstart, N, G);

    // weight conversion (19 matrices)
    TA ta;
    for (int l = 0; l < 3; ++l) {
        ta.d[l * 4 + 0] = { Wq    + (size_t)l * 16384, QKVS_OFF + l * 65536 + 0,     128, 128 };
        ta.d[l * 4 + 1] = { Wk    + (size_t)l * 16384, QKVS_OFF + l * 65536 + 16384, 128, 128 };
        ta.d[l * 4 + 2] = { Wv    + (size_t)l * 16384, QKVS_OFF + l * 65536 + 32768, 128, 128 };
        ta.d[l * 4 + 3] = { Wskip + (size_t)l * 16384, QKVS_OFF + l * 65536 + 49152, 128, 128 };
        ta.d[12 + l]    = { Wf1   + (size_t)l * 32768, F1_OFF   + l * 32768,         128, 256 };
        ta.d[15 + l]    = { Wf2   + (size_t)l * 32768, F2_OFF   + l * 32768,         256, 128 };
    }
    ta.d[18] = { Wg1, G1_OFF, 384, 128 };
    dim3 wg(cdiv(49152, 256), 19);
    wconv_kernel<<<wg, 256, 0, stream>>>(ta, WT);

    input_proj_kernel<<<cdiv(N * 64, 256), 256, 0, stream>>>(x, Win, b_in, xc, JK, N);

    int gb = cdiv(N, 128);
    int nb16 = cdiv(N, 16);
    int nb4 = cdiv(N, 4);
    for (int l = 0; l < LAYERS; ++l) {
        const u16* hin = xc + (size_t)((l == 0) ? 0 : (l - 1) * H);
        // fused q|k|v|skip: q,k,v -> bf16 qkv; skip -> bf16 skipb
        gemm_mfma<0, 4><<<gb * 4, 256, 0, stream>>>(
            hin, JK, WT + QKVS_OFF + (size_t)l * 65536, 128,
            bq + l * H, bk + l * H, bv + l * H, bskip + l * H,
            nullptr, qkv, skipb, nullptr, N);
        attn_kernel<<<nb16, 256, 0, stream>>>(qkv, hin, JK, skipb, offsets, psrc, pe,
                                              We + (size_t)l * 4 * H, ln1_g + l * H, ln1_b + l * H,
                                              N);
        // FF1: A = ln1 bf16 (qkv cols 0..127) -> relu out bf16 at qkv cols 128..383
        gemm_mfma<1, 2><<<gb * 2, 256, 0, stream>>>(
            qkv, JK, WT + F1_OFF + (size_t)l * 32768, 128,
            bf1 + (size_t)l * FFDIM, nullptr, nullptr, nullptr,
            nullptr, qkv + H, nullptr, nullptr, N);
        // FF2: A = ff1 bf16 (qkv cols 128..383), resid = LN1 bf16 (qkv cols 0..127), out hmid f32
        gemm_mfma<2, 1><<<gb, 256, 0, stream>>>(
            qkv + H, JK, WT + F2_OFF + (size_t)l * 32768, 256,
            bf2 + (size_t)l * H, nullptr, nullptr, nullptr,
            qkv, nullptr, nullptr, hmid, N);
        ln_kernel<<<nb4, 256, 0, stream>>>(hmid, ln2_g + l * H, ln2_b + l * H,
                                           xc + (size_t)l * H, JK, N);
    }

    // gate: A = xc bf16 K=384, fused relu+dot(Wg2)+bg2 -> gate[n]
    gemm_mfma<3, 1><<<gb, 256, 0, stream>>>(
        xc, JK, WT + G1_OFF, JK,
        bg1, Wg2, bg2, nullptr,
        nullptr, nullptr, nullptr, gate, N);
    pool_kernel<<<G, 256, 0, stream>>>(gate, xc, gstart, u, pooled, G);
    head_kernel<<<G, 128, 0, stream>>>(pooled, Wh1, bh1, Wh2, bh2, (float*)d_out, G);
}